// Round 9
// baseline (1619.721 us; speedup 1.0000x reference)
//
#include <hip/hip_runtime.h>
#include <math.h>

#define BB 32
#define HH_ 128
#define WW_ 256

typedef _Float16 f16_t;
typedef _Float16 half8 __attribute__((ext_vector_type(8)));
typedef float floatx4 __attribute__((ext_vector_type(4)));

__device__ __forceinline__ float gelu_f(float v){
  return 0.5f * v * (1.0f + erff(v * 0.70710678118654752f));
}

__global__ void k_diag(float* out, float v){ out[threadIdx.x] = v; }

// -------- twiddle tables + head-weight f16 conversion (merged) --------------
__global__ void k_tables(float2* twf, float2* thf, float2* thi, f16_t* twzh,
      const float* __restrict__ f1_w, const float* __restrict__ f2_w,
      const float* __restrict__ f3_w, f16_t* f1T, f16_t* f2T, f16_t* f3T){
  int t = blockIdx.x*256 + threadIdx.x;
  const double PI2 = 6.283185307179586476925286766559;
  if (t < 3072){                       // forward w-DFT: [w][ky]
    int w = t/12, ky = t%12;
    double a = -PI2 * (double)(w*ky) / 256.0;
    twf[t] = make_float2((float)cos(a), (float)sin(a));
  } else if (t < 6144){                // forward h-DFT: [h][j], kx {0..11,116..127}
    int f = t-3072; int h = f/24, j = f%24;
    int kx = (j<12)? j : j+104;
    double a = -PI2 * (double)(h*kx) / 128.0;
    thf[f] = make_float2((float)cos(a), (float)sin(a));
  } else if (t < 9216){                // inverse h (includes 1/128)
    int f = t-6144; int h = f/24, j = f%24;
    int kx = (j<12)? j : j+104;
    double a = PI2 * (double)(h*kx) / 128.0;
    thi[f] = make_float2((float)(cos(a)/128.0), (float)(sin(a)/128.0));
  } else if (t < 12288){               // inverse w (c2r) coefs, f16, [w][32]
    int f = t-9216; int w = f/12, ky = f%12;
    double a = PI2 * (double)(w*ky) / 256.0;
    double s = (ky==0)? 1.0 : 2.0;
    twzh[w*32 + ky]      = (f16_t)( s*cos(a)/256.0);
    twzh[w*32 + 12 + ky] = (f16_t)(-s*sin(a)/256.0);
    if (ky < 8) twzh[w*32 + 24 + ky] = (f16_t)0.f;
  } else {
    int t2 = t - 12288;                // head weights -> f16
    if (t2 < 8192) f1T[t2] = (f16_t)f1_w[t2];
    else if (t2 < 16384) f2T[t2-8192] = (f16_t)f2_w[t2-8192];
    else if (t2 < 16512) f3T[t2-16384] = (f16_t)f3_w[t2-16384];
  }
}

// ------- conv weight transpose via LDS (coalesced both sides) ---------------
__global__ __launch_bounds__(256) void k_wprep(const float* __restrict__ tw,
                                               f16_t* __restrict__ wT){
  __shared__ float s[9216];                 // [o16][c][tap] for one (tt, og)
  int blk = blockIdx.x;                     // 56 = 14 tt x 4 og
  int og = blk & 3, tt = blk >> 2;
  int tid = threadIdx.x;
  const float* src = tw + (long)tt*36864 + og*9216;
  for (int f = tid; f < 9216; f += 256) s[f] = src[f];
  __syncthreads();
  for (int f = tid; f < 9216; f += 256){
    int c = f & 63; int r = f >> 6;
    int o16 = r % 16, tap = r / 16;
    float v = s[(o16*64 + c)*9 + tap];
    wT[(((long)tt*9 + tap)*64 + og*16 + o16)*64 + c] = (f16_t)v;
  }
}

// ------- spectral weight transpose via LDS (coalesced both sides) -----------
__global__ __launch_bounds__(256) void k_mixprep(const float* __restrict__ w1r,
      const float* __restrict__ w1i, const float* __restrict__ w2r,
      const float* __restrict__ w2i, float2* __restrict__ wmix){
  __shared__ float sr[6656], si[6656];      // [i8][o][ky] padded to 13
  int blk = blockIdx.x;                     // 768 = l(4) x sel(2) x kx(12) x ig(8)
  int ig  = blk & 7;
  int kx  = (blk >> 3) % 12;
  int sel = (blk / 96) & 1;
  int l   = blk / 192;
  const float* wr = sel ? w2r : w1r;
  const float* wi = sel ? w2i : w1i;
  int tid = threadIdx.x;
  for (int f = tid; f < 6144; f += 256){
    int i8 = f / 768; int rem = f % 768;
    int o = rem / 12, ky = rem % 12;
    long addr = (((long)l*64 + ig*8 + i8)*64 + o)*144 + kx*12 + ky;
    sr[(i8*64 + o)*13 + ky] = wr[addr];
    si[(i8*64 + o)*13 + ky] = wi[addr];
  }
  __syncthreads();
  int j = sel ? (kx + 12) : kx;
  for (int f = tid; f < 6144; f += 256){
    int o = f & 63; int r = f >> 6;
    int ky = r % 12, i8 = r / 12;
    int sidx = (i8*64 + o)*13 + ky;
    wmix[(((long)l*288 + j*12 + ky))*4096 + (ig*8 + i8)*64 + o] =
        make_float2(sr[sidx], si[sidx]);
  }
}

// ---------------- ext gate + g (B x HW), ext MLP fused ----------------------
__global__ __launch_bounds__(256) void k_g(const float* __restrict__ ext,
      const float* __restrict__ day_emb, const float* __restrict__ hour_emb,
      const float* __restrict__ e1_w, const float* __restrict__ e1_b,
      const float* __restrict__ e2_w, const float* __restrict__ e2_b,
      float* __restrict__ g){
  int b = blockIdx.y;
  int hw = blockIdx.x*256 + threadIdx.x;
  __shared__ float s[64];
  if (threadIdx.x < 64){
    int j = threadIdx.x;
    const float* e = ext + b*6;
    float emb[6];
    emb[0] = e[0];
    int d  = (int)e[2];
    emb[1] = day_emb[d*2];  emb[2] = day_emb[d*2+1];
    int hr = (int)e[3];
    emb[3] = hour_emb[hr*3]; emb[4] = hour_emb[hr*3+1]; emb[5] = hour_emb[hr*3+2];
    float acc = e1_b[j];
    #pragma unroll
    for (int k = 0; k < 6; k++) acc += emb[k]*e1_w[j*6+k];
    s[j] = gelu_f(acc);
  }
  __syncthreads();
  const float4* wrow = (const float4*)(e2_w + (long)hw*64);
  float acc = e2_b[hw];
  #pragma unroll
  for (int k = 0; k < 16; k++){
    float4 v = wrow[k];
    acc += v.x*s[4*k] + v.y*s[4*k+1] + v.z*s[4*k+2] + v.w*s[4*k+3];
  }
  g[(long)b*(HH_*WW_) + hw] = gelu_f(acc);
}

// ---------------- encoder: x[b,h,w,c] f16 -----------------------------------
__global__ __launch_bounds__(256) void k_enc(const float* __restrict__ inp,
      const float* __restrict__ g, const float* __restrict__ enc_w,
      const float* __restrict__ enc_b, f16_t* __restrict__ x){
  long t = (long)blockIdx.x*256 + threadIdx.x;   // < B*HW*64
  int c = (int)(t & 63);
  long pix = t >> 6;
  const float* ip = inp + pix*4;
  const float* wr = enc_w + c*5;
  float acc = enc_b[c] + ip[0]*wr[0] + ip[1]*wr[1] + ip[2]*wr[2] + ip[3]*wr[3] + g[pix]*wr[4];
  x[t] = (f16_t)acc;
}

// ---------------- forward DFT along w (layer 0 only): fp0 -------------------
__global__ __launch_bounds__(256) void k_dft_w(const f16_t* __restrict__ x,
      const float4* __restrict__ twf4, float2* __restrict__ fft1){
  __shared__ float4 tw[1536];                      // [w][6]
  for (int f = threadIdx.x; f < 1536; f += 256) tw[f] = twf4[f];
  __syncthreads();
  int wave = threadIdx.x >> 6, lane = threadIdx.x & 63;
  long row = (long)blockIdx.x*4 + wave;            // b*H + h
  const f16_t* xr = x + row*16384 + lane;
  float ar[12], ai[12];
  #pragma unroll
  for (int k = 0; k < 12; k++){ ar[k] = 0.f; ai[k] = 0.f; }
  for (int w = 0; w < 256; w++){
    float xv = (float)xr[(long)w*64];
    const float4* t = &tw[w*6];
    #pragma unroll
    for (int k = 0; k < 6; k++){
      float4 tv = t[k];
      ar[2*k]   += xv*tv.x;  ai[2*k]   += xv*tv.y;
      ar[2*k+1] += xv*tv.z;  ai[2*k+1] += xv*tv.w;
    }
  }
  float2* op = fft1 + row*768 + lane;
  #pragma unroll
  for (int ky = 0; ky < 12; ky++) op[ky*64] = make_float2(ar[ky], ai[ky]);
}

// ------- forward DFT along h, dual-source sum, 768 blocks -------------------
__global__ __launch_bounds__(256) void k_dft_h(const float2* __restrict__ s0,
      const float2* __restrict__ s1, int dual,
      const float2* __restrict__ thf, float2* __restrict__ xft){
  __shared__ float2 th[3072];                      // [h][24]
  __shared__ float2 xch[2048];                     // [32 h][64 c]
  int tid = threadIdx.x;
  for (int f = tid; f < 3072; f += 256) th[f] = thf[f];
  int blk = blockIdx.x;                            // < 768
  int b = blk / 24, r = blk % 24;
  int ky = r % 12, jh = r / 12;                    // j half
  int wv = tid >> 6, lane = tid & 63;
  float2 acc[3];
  #pragma unroll
  for (int q = 0; q < 3; q++) acc[q] = make_float2(0.f, 0.f);
  long base = (long)b*98304 + ky*64;
  for (int ch = 0; ch < 4; ch++){
    __syncthreads();
    for (int f = tid; f < 2048; f += 256){
      int hh = f >> 6, c = f & 63;
      long idx = base + (long)(ch*32 + hh)*768 + c;
      float2 v = s0[idx];
      if (dual){ float2 u = s1[idx]; v.x += u.x; v.y += u.y; }
      xch[f] = v;
    }
    __syncthreads();
    for (int hh = 0; hh < 32; hh++){
      float2 v = xch[hh*64 + lane];
      int hg = ch*32 + hh;
      #pragma unroll
      for (int q = 0; q < 3; q++){
        float2 t = th[hg*24 + jh*12 + q*4 + wv];
        acc[q].x += t.x*v.x - t.y*v.y;
        acc[q].y += t.x*v.y + t.y*v.x;
      }
    }
  }
  #pragma unroll
  for (int q = 0; q < 3; q++){
    int j = jh*12 + q*4 + wv;
    xft[((long)b*288 + j*12 + ky)*64 + lane] = acc[q];
  }
}

// -------- mode mixing IN PLACE (coalesced weights), 576 blocks --------------
__global__ __launch_bounds__(256) void k_mix(const float2* __restrict__ wmix,
      int layer, float2* __restrict__ xft){
  __shared__ float2 wl[4096];                      // [i][o]
  int jk = blockIdx.x >> 1;
  int bh2 = blockIdx.x & 1;
  int j = jk / 12, ky = jk % 12;
  const float2* wsrc = wmix + ((long)layer*288 + jk)*4096;
  for (int f = threadIdx.x; f < 4096; f += 256) wl[f] = wsrc[f];
  __syncthreads();
  int wave = threadIdx.x >> 6, lane = threadIdx.x & 63;
  for (int b = bh2*16 + wave; b < bh2*16 + 16; b += 4){
    long base = ((long)b*288 + j*12 + ky)*64;
    float2 mine = xft[base + lane];
    float re = 0.f, im = 0.f;
    #pragma unroll 8
    for (int i = 0; i < 64; i++){
      float vr = __shfl(mine.x, i);
      float vi = __shfl(mine.y, i);
      float2 ww = wl[i*64 + lane];
      re += vr*ww.x - vi*ww.y;
      im += vr*ww.y + vi*ww.x;
    }
    xft[base + lane] = make_float2(re, im);
  }
}

// ------- inverse DFT along h, 768 blocks ------------------------------------
__global__ __launch_bounds__(256) void k_ifft_h(const float2* __restrict__ c3,
      const float2* __restrict__ thi, float2* __restrict__ zi){
  __shared__ float2 th[3072];                      // [h][24]
  int tid = threadIdx.x;
  for (int f = tid; f < 3072; f += 256) th[f] = thi[f];
  int blk = blockIdx.x;                            // < 768
  int b = blk / 24, r = blk % 24;
  int ky = r % 12, hh2 = r / 12;                   // h half
  int wv = tid >> 6, lane = tid & 63;
  float2 cr[24];
  const float2* src = c3 + (long)b*18432 + ky*64 + lane;
  #pragma unroll
  for (int j = 0; j < 24; j++) cr[j] = src[(long)j*768];
  __syncthreads();
  for (int q = 0; q < 16; q++){
    int h = hh2*64 + q*4 + wv;
    float re = 0.f, im = 0.f;
    #pragma unroll
    for (int j = 0; j < 24; j++){
      float2 t = th[h*24 + j];
      re += t.x*cr[j].x - t.y*cr[j].y;
      im += t.x*cr[j].y + t.y*cr[j].x;
    }
    zi[((long)b*128 + h)*768 + ky*64 + lane] = make_float2(re, im);
  }
}

// ------- MFMA: inverse-w + skip + bias + (gelu), in place on x,
//         fused next-layer partial w-DFT (LDS-staged twiddles) ---------------
__global__ __launch_bounds__(256) void k_iw_mfma(f16_t* __restrict__ x,
      const float2* __restrict__ zi, const float* __restrict__ ws_w,
      const float* __restrict__ ws_b, const f16_t* __restrict__ twzh,
      const float4* __restrict__ twf4g, float2* __restrict__ fp0,
      float2* __restrict__ fp1, int layer, int act, int dodft){
  __shared__ __align__(16) char sm[52736];
  f16_t* A  = (f16_t*)sm;                   // [128][136] phase1
  f16_t* Bm = (f16_t*)(sm + 34816);         // [64][136]  phase1
  float* sb = (float*)(sm + 52224);         // [64]
  f16_t* Ob  = (f16_t*)sm;                  // [128][72]  phase2 (18432 B)
  float2* ps = (float2*)(sm + 18432);       // 2 x 768 float2    (12288 B)
  float4* twl= (float4*)(sm + 30720);       // [128][6] float4   (12288 B)
  int tid = threadIdx.x;
  int blk = blockIdx.x;
  int half = blk & 1;
  long bh = blk >> 1;                       // b*128 + h
  int w0 = half*128;
  const f16_t* xrow = x + (bh*256 + w0)*64;
  for (int f = tid; f < 1024; f += 256){    // x part, 16B copies
    int px = f >> 3, c8 = (f & 7)*8;
    *(float4*)((char*)A + (px*136 + c8)*2) = *(const float4*)(xrow + px*64 + c8);
  }
  for (int f = tid; f < 3072; f += 256){    // twz part (duplicated hi/lo)
    int px = f/24, k = f%24;
    f16_t v = twzh[(w0+px)*32 + k];
    A[px*136 + 64 + k] = v;
    A[px*136 + 88 + k] = v;
  }
  for (int f = tid; f < 3072; f += 256){    // A zero pad k=112..135
    int px = f/24, k = f%24;
    A[px*136 + 112 + k] = (f16_t)0.f;
  }
  const float* wsl = ws_w + (long)layer*4096;
  for (int f = tid; f < 1024; f += 256){    // B ws part
    int o = f >> 4, c4 = f & 15;
    float4 v = *(const float4*)(wsl + o*64 + c4*4);
    f16_t* d = Bm + o*136 + c4*4;
    d[0]=(f16_t)v.x; d[1]=(f16_t)v.y; d[2]=(f16_t)v.z; d[3]=(f16_t)v.w;
  }
  const float2* zrow = zi + bh*768;
  for (int f = tid; f < 768; f += 256){     // B z hi/lo
    int o = f & 63, ky = f >> 6;
    float2 v = zrow[ky*64 + o];
    f16_t hr = (f16_t)v.x; f16_t hi_ = (f16_t)v.y;
    Bm[o*136 + 64 + ky] = hr;
    Bm[o*136 + 76 + ky] = hi_;
    Bm[o*136 + 88 + ky] = (f16_t)(v.x - (float)hr);
    Bm[o*136 +100 + ky] = (f16_t)(v.y - (float)hi_);
  }
  for (int f = tid; f < 1536; f += 256){    // B zero pad
    int o = f/24, k = f%24;
    Bm[o*136 + 112 + k] = (f16_t)0.f;
  }
  if (tid < 64) sb[tid] = ws_b[layer*64 + tid];
  __syncthreads();
  int lane = tid & 63, wv = tid >> 6;
  int n15 = lane & 15, quad = lane >> 4;
  int n = wv*16 + n15;
  half8 bfr[4];
  #pragma unroll
  for (int kc = 0; kc < 4; kc++)
    bfr[kc] = *(const half8*)(Bm + n*136 + kc*32 + quad*8);
  floatx4 acc[8];
  #pragma unroll
  for (int mt = 0; mt < 8; mt++){
    floatx4 c = {0.f,0.f,0.f,0.f};
    #pragma unroll
    for (int kc = 0; kc < 4; kc++){
      half8 a = *(const half8*)(A + (mt*16 + n15)*136 + kc*32 + quad*8);
      c = __builtin_amdgcn_mfma_f32_16x16x32_f16(a, bfr[kc], c, 0, 0, 0);
    }
    acc[mt] = c;
  }
  float bias = sb[n];
  __syncthreads();                           // A/Bm dead -> Ob, ps, twl
  #pragma unroll
  for (int mt = 0; mt < 8; mt++){
    #pragma unroll
    for (int r = 0; r < 4; r++){
      int m = mt*16 + quad*4 + r;
      float v = acc[mt][r] + bias;
      if (act) v = gelu_f(v);
      Ob[m*72 + n] = (f16_t)v;
    }
  }
  if (dodft){                                // stage this half-row's twiddles
    const float4* tsrc = twf4g + w0*6;
    for (int f = tid; f < 768; f += 256) twl[f] = tsrc[f];
  }
  __syncthreads();
  f16_t* xo = x + (bh*256 + w0)*64;
  for (int f = tid; f < 1024; f += 256){     // vectorized write-back
    int px = f >> 3, c8 = (f & 7)*8;
    *(float4*)(xo + px*64 + c8) = *(const float4*)((char*)Ob + (px*72 + c8)*2);
  }
  if (dodft){                                // partial w-DFT of this half-row
    int wl0 = wv*32;
    float ar[12], ai[12];
    #pragma unroll
    for (int k = 0; k < 12; k++){ ar[k] = 0.f; ai[k] = 0.f; }
    for (int i2 = 0; i2 < 32; i2++){
      int wl = wl0 + i2;
      float xv = (float)Ob[wl*72 + lane];
      const float4* t = &twl[wl*6];
      #pragma unroll
      for (int k = 0; k < 6; k++){
        float4 tv = t[k];
        ar[2*k]   += xv*tv.x;  ai[2*k]   += xv*tv.y;
        ar[2*k+1] += xv*tv.z;  ai[2*k+1] += xv*tv.w;
      }
    }
    if (wv < 2){                             // waves 0,1 write slots
      #pragma unroll
      for (int k = 0; k < 12; k++)
        ps[wv*768 + k*64 + lane] = make_float2(ar[k], ai[k]);
    }
    __syncthreads();
    if (wv >= 2){                            // waves 2,3 accumulate
      #pragma unroll
      for (int k = 0; k < 12; k++){
        int idx = (wv-2)*768 + k*64 + lane;
        float2 v = ps[idx];
        ps[idx] = make_float2(v.x + ar[k], v.y + ai[k]);
      }
    }
    __syncthreads();
    float2* dst = half ? fp1 : fp0;
    for (int f = tid; f < 768; f += 256){
      float2 a0 = ps[f], a1 = ps[768 + f];
      dst[bh*768 + f] = make_float2(a0.x + a1.x, a0.y + a1.y);
    }
  }
}

// ------- MFMA conv 3x3 (per-batch weights) + gelu + head, fused; 64-px tiles -
__global__ __launch_bounds__(256) void k_conv_head(const f16_t* __restrict__ x,
      const float* __restrict__ ext, const f16_t* __restrict__ wT,
      const float* __restrict__ tb, const f16_t* __restrict__ f1T,
      const float* __restrict__ f1_b, const f16_t* __restrict__ f2T,
      const float* __restrict__ f2_b, const f16_t* __restrict__ f3T,
      const float* __restrict__ f3_b, float* __restrict__ out){
  __shared__ __align__(16) char sm[37632];
  f16_t* hf   = (f16_t*)sm;                 // [64][72]   9216
  f16_t* z1   = (f16_t*)(sm + 9216);        // [64][136]  17408
  f16_t* z2   = (f16_t*)(sm + 26624);       // [64][72]   9216
  float* tbs  = (float*)(sm + 35840);       // 64
  float* f1bs = (float*)(sm + 36096);       // 128
  float* f2bs = (float*)(sm + 36608);       // 64
  f16_t* f3s  = (f16_t*)(sm + 36864);       // 128 f16
  float* f3bs = (float*)(sm + 37120);       // 2
  f16_t* xt   = (f16_t*)sm;                 // [3][66][72] = 28512 B (conv phase)

  int tid = threadIdx.x;
  int blk = blockIdx.x;
  int wc = blk & 3, h = (blk >> 2) & 127, b = blk >> 9;
  int w0 = wc*64;
  int t_idx = (int)ext[b*6+3] - 5;

  if (tid < 64) tbs[tid] = tb[t_idx*64 + tid];
  else if (tid < 192) f1bs[tid-64] = f1_b[tid-64];
  else f2bs[tid-192] = f2_b[tid-192];
  if (tid < 128) f3s[tid] = f3T[tid];
  if (tid < 2) f3bs[tid] = f3_b[tid];

  for (int f = tid; f < 3168; f += 256){    // xt: 3 rows x 66 px x 64 c
    int c4 = f & 15, r = f >> 4;
    int dy = r/66, pxl = r%66;
    int hh = h - 1 + dy, wg = w0 - 1 + pxl;
    ushort4 v = {0,0,0,0};
    if (hh >= 0 && hh < HH_ && wg >= 0 && wg < WW_)
      v = *(const ushort4*)(x + (((long)b*HH_ + hh)*WW_ + wg)*64 + c4*4);
    *(ushort4*)((unsigned short*)xt + (dy*66 + pxl)*72 + c4*4) = v;
  }
  __syncthreads();

  int lane = tid & 63, wv = tid >> 6;
  int n15 = lane & 15, quad = lane >> 4;

  floatx4 acc[4];
  #pragma unroll
  for (int mt = 0; mt < 4; mt++) acc[mt] = (floatx4){0.f,0.f,0.f,0.f};
  const f16_t* wTt = wT + (long)t_idx*36864;
  for (int tap = 0; tap < 9; tap++){
    int dy = tap/3, dx = tap%3;
    const f16_t* wrow = wTt + (tap*64 + wv*16 + n15)*64;
    #pragma unroll
    for (int kc = 0; kc < 2; kc++){
      half8 bfrag = *(const half8*)(wrow + kc*32 + quad*8);
      #pragma unroll
      for (int mt = 0; mt < 4; mt++){
        int p = mt*16 + n15 + dx;
        half8 a = *(const half8*)(xt + (dy*66 + p)*72 + kc*32 + quad*8);
        acc[mt] = __builtin_amdgcn_mfma_f32_16x16x32_f16(a, bfrag, acc[mt], 0,0,0);
      }
    }
  }
  __syncthreads();                           // xt dead
  {
    int n = wv*16 + n15;
    float bias = tbs[n];
    #pragma unroll
    for (int mt = 0; mt < 4; mt++){
      #pragma unroll
      for (int r = 0; r < 4; r++){
        int m = mt*16 + quad*4 + r;
        hf[m*72 + n] = (f16_t)gelu_f(acc[mt][r] + bias);
      }
    }
  }
  __syncthreads();
  // z1 = gelu(hf . f1^T + f1_b): M=64 N=128 K=64
  #pragma unroll
  for (int nt = 0; nt < 2; nt++){
    int n = wv*32 + nt*16 + n15;
    float bias = f1bs[n];
    half8 bf0 = *(const half8*)(f1T + n*64 + quad*8);
    half8 bf1 = *(const half8*)(f1T + n*64 + 32 + quad*8);
    #pragma unroll
    for (int mt = 0; mt < 4; mt++){
      floatx4 c = {0.f,0.f,0.f,0.f};
      half8 a0 = *(const half8*)(hf + (mt*16 + n15)*72 + quad*8);
      half8 a1 = *(const half8*)(hf + (mt*16 + n15)*72 + 32 + quad*8);
      c = __builtin_amdgcn_mfma_f32_16x16x32_f16(a0, bf0, c, 0,0,0);
      c = __builtin_amdgcn_mfma_f32_16x16x32_f16(a1, bf1, c, 0,0,0);
      #pragma unroll
      for (int r = 0; r < 4; r++){
        int m = mt*16 + quad*4 + r;
        z1[m*136 + n] = (f16_t)gelu_f(c[r] + bias);
      }
    }
  }
  __syncthreads();
  // z2 = gelu(z1 . f2^T + f2_b): M=64 N=64 K=128
  {
    int n = wv*16 + n15;
    float bias = f2bs[n];
    half8 bf[4];
    #pragma unroll
    for (int kc = 0; kc < 4; kc++)
      bf[kc] = *(const half8*)(f2T + n*128 + kc*32 + quad*8);
    #pragma unroll
    for (int mt = 0; mt < 4; mt++){
      floatx4 c = {0.f,0.f,0.f,0.f};
      #pragma unroll
      for (int kc = 0; kc < 4; kc++){
        half8 a = *(const half8*)(z1 + (mt*16 + n15)*136 + kc*32 + quad*8);
        c = __builtin_amdgcn_mfma_f32_16x16x32_f16(a, bf[kc], c, 0,0,0);
      }
      #pragma unroll
      for (int r = 0; r < 4; r++){
        int m = mt*16 + quad*4 + r;
        z2[m*72 + n] = (f16_t)gelu_f(c[r] + bias);
      }
    }
  }
  __syncthreads();
  // f3: out[px][0..1]
  if (tid < 128){
    int px = tid >> 1, oo = tid & 1;
    const f16_t* zr = z2 + px*72;
    const f16_t* fr = f3s + oo*64;
    float a = f3bs[oo];
    #pragma unroll
    for (int g = 0; g < 8; g++){
      half8 zv = *(const half8*)(zr + g*8);
      half8 wv2 = *(const half8*)(fr + g*8);
      #pragma unroll
      for (int q = 0; q < 8; q++) a += (float)zv[q]*(float)wv2[q];
    }
    out[(((long)b*HH_ + h)*WW_ + w0 + px)*2 + oo] = a;
  }
}

extern "C" void kernel_launch(void* const* d_in, const int* in_sizes, int n_in,
                              void* d_out, int out_size, void* d_ws, size_t ws_size,
                              hipStream_t stream){
  const float* inp     = (const float*)d_in[0];
  const float* ext     = (const float*)d_in[1];
  const float* enc_w   = (const float*)d_in[2];
  const float* enc_b   = (const float*)d_in[3];
  const float* w1r     = (const float*)d_in[4];
  const float* w1i     = (const float*)d_in[5];
  const float* w2r     = (const float*)d_in[6];
  const float* w2i     = (const float*)d_in[7];
  const float* ws_w    = (const float*)d_in[8];
  const float* ws_b    = (const float*)d_in[9];
  const float* day_emb = (const float*)d_in[10];
  const float* hour_emb= (const float*)d_in[11];
  const float* e1_w    = (const float*)d_in[12];
  const float* e1_b    = (const float*)d_in[13];
  const float* e2_w    = (const float*)d_in[14];
  const float* e2_b    = (const float*)d_in[15];
  const float* tw      = (const float*)d_in[16];
  const float* tb      = (const float*)d_in[17];
  const float* f1_w    = (const float*)d_in[18];
  const float* f1_b    = (const float*)d_in[19];
  const float* f2_w    = (const float*)d_in[20];
  const float* f2_b    = (const float*)d_in[21];
  const float* f3_w    = (const float*)d_in[22];
  const float* f3_b    = (const float*)d_in[23];
  float* outp = (float*)d_out;

  const size_t need = 257532160;
  if (ws_size < need){
    k_diag<<<dim3(1), dim3(64), 0, stream>>>(outp, (float)(ws_size >> 20));
    return;
  }
  char* p = (char*)d_ws;
  f16_t*  x    = (f16_t*)(p);                    // 134217728 B
  float2* fp0  = (float2*)(p + 134217728);       // 25165824 B
  float2* fp1  = (float2*)(p + 159383552);       // 25165824 B
  float2* zi   = (float2*)(p + 184549376);       // 25165824 B
  float2* xft  = (float2*)(p + 209715200);       // 4718592 B
  float*  g    = (float*)(p + 214433792);        // 4194304 B
  float2* twf  = (float2*)(p + 218628096);       // 24576 B
  float2* thf  = (float2*)(p + 218652672);       // 24576 B
  float2* thi  = (float2*)(p + 218677248);       // 24576 B
  f16_t*  twzh = (f16_t*)(p + 218701824);        // 16384 B
  f16_t*  wT   = (f16_t*)(p + 218718208);        // 1032192 B
  f16_t*  f1T  = (f16_t*)(p + 219750400);        // 16384 B
  f16_t*  f2T  = (f16_t*)(p + 219766784);        // 16384 B
  f16_t*  f3T  = (f16_t*)(p + 219783168);        // 256 B
  float2* wmix = (float2*)(p + 219783424);       // 37748736 B

  k_tables<<<dim3(113), dim3(256), 0, stream>>>(twf, thf, thi, twzh,
                                                f1_w, f2_w, f3_w, f1T, f2T, f3T);
  k_wprep<<<dim3(56), dim3(256), 0, stream>>>(tw, wT);
  k_mixprep<<<dim3(768), dim3(256), 0, stream>>>(w1r, w1i, w2r, w2i, wmix);
  k_g<<<dim3(128, 32), dim3(256), 0, stream>>>(ext, day_emb, hour_emb,
                                               e1_w, e1_b, e2_w, e2_b, g);
  k_enc<<<dim3(262144), dim3(256), 0, stream>>>(inp, g, enc_w, enc_b, x);
  k_dft_w<<<dim3(1024), dim3(256), 0, stream>>>(x, (const float4*)twf, fp0);
  for (int l = 0; l < 4; l++){
    k_dft_h<<<dim3(768), dim3(256), 0, stream>>>(fp0, fp1, (l > 0) ? 1 : 0,
                                                 thf, xft);
    k_mix<<<dim3(576), dim3(256), 0, stream>>>(wmix, l, xft);
    k_ifft_h<<<dim3(768), dim3(256), 0, stream>>>(xft, thi, zi);
    k_iw_mfma<<<dim3(8192), dim3(256), 0, stream>>>(x, zi, ws_w, ws_b, twzh,
                       (const float4*)twf, fp0, fp1,
                       l, (l < 3) ? 1 : 0, (l < 3) ? 1 : 0);
  }
  k_conv_head<<<dim3(16384), dim3(256), 0, stream>>>(x, ext, wT, tb,
                     f1T, f1_b, f2T, f2_b, f3T, f3_b, outp);
}

// Round 10
// 1507.196 us; speedup vs baseline: 1.0747x; 1.0747x over previous
//
#include <hip/hip_runtime.h>
#include <math.h>

#define BB 32
#define HH_ 128
#define WW_ 256

typedef _Float16 f16_t;
typedef _Float16 half8 __attribute__((ext_vector_type(8)));
typedef float floatx4 __attribute__((ext_vector_type(4)));

__device__ __forceinline__ float gelu_f(float v){
  return 0.5f * v * (1.0f + erff(v * 0.70710678118654752f));
}

__global__ void k_diag(float* out, float v){ out[threadIdx.x] = v; }

// ---- merged prep: [0,113) tables+head-f16; [113,169) wprep; [169,937) mixprep
__global__ __launch_bounds__(256) void k_prep(
      float2* twf, float2* thf, float2* thi, f16_t* twzh,
      const float* __restrict__ f1_w, const float* __restrict__ f2_w,
      const float* __restrict__ f3_w, f16_t* f1T, f16_t* f2T, f16_t* f3T,
      const float* __restrict__ tw, f16_t* __restrict__ wT,
      const float* __restrict__ w1r, const float* __restrict__ w1i,
      const float* __restrict__ w2r, const float* __restrict__ w2i,
      float2* __restrict__ wmix){
  __shared__ __align__(16) char smp[53248];
  int blk = blockIdx.x, tid = threadIdx.x;
  if (blk < 113){
    int t = blk*256 + tid;
    const double PI2 = 6.283185307179586476925286766559;
    if (t < 3072){                       // forward w-DFT: [w][ky]
      int w = t/12, ky = t%12;
      double a = -PI2 * (double)(w*ky) / 256.0;
      twf[t] = make_float2((float)cos(a), (float)sin(a));
    } else if (t < 6144){                // forward h-DFT: [h][j]
      int f = t-3072; int h = f/24, j = f%24;
      int kx = (j<12)? j : j+104;
      double a = -PI2 * (double)(h*kx) / 128.0;
      thf[f] = make_float2((float)cos(a), (float)sin(a));
    } else if (t < 9216){                // inverse h (includes 1/128)
      int f = t-6144; int h = f/24, j = f%24;
      int kx = (j<12)? j : j+104;
      double a = PI2 * (double)(h*kx) / 128.0;
      thi[f] = make_float2((float)(cos(a)/128.0), (float)(sin(a)/128.0));
    } else if (t < 12288){               // inverse w (c2r) coefs, f16
      int f = t-9216; int w = f/12, ky = f%12;
      double a = PI2 * (double)(w*ky) / 256.0;
      double s = (ky==0)? 1.0 : 2.0;
      twzh[w*32 + ky]      = (f16_t)( s*cos(a)/256.0);
      twzh[w*32 + 12 + ky] = (f16_t)(-s*sin(a)/256.0);
      if (ky < 8) twzh[w*32 + 24 + ky] = (f16_t)0.f;
    } else {
      int t2 = t - 12288;                // head weights -> f16
      if (t2 < 8192) f1T[t2] = (f16_t)f1_w[t2];
      else if (t2 < 16384) f2T[t2-8192] = (f16_t)f2_w[t2-8192];
      else if (t2 < 16512) f3T[t2-16384] = (f16_t)f3_w[t2-16384];
    }
  } else if (blk < 169){                 // conv weight transpose via LDS
    float* s = (float*)smp;              // [o16][c][tap]
    int b2 = blk - 113;
    int og = b2 & 3, tt = b2 >> 2;
    const float* src = tw + (long)tt*36864 + og*9216;
    for (int f = tid; f < 9216; f += 256) s[f] = src[f];
    __syncthreads();
    for (int f = tid; f < 9216; f += 256){
      int c = f & 63; int r = f >> 6;
      int o16 = r % 16, tap = r / 16;
      float v = s[(o16*64 + c)*9 + tap];
      wT[(((long)tt*9 + tap)*64 + og*16 + o16)*64 + c] = (f16_t)v;
    }
  } else {                               // spectral weight transpose via LDS
    float* sr = (float*)smp;             // 6656 f
    float* si = (float*)(smp + 26624);   // 6656 f
    int b2 = blk - 169;                  // < 768
    int ig  = b2 & 7;
    int kx  = (b2 >> 3) % 12;
    int sel = (b2 / 96) & 1;
    int l   = b2 / 192;
    const float* wr = sel ? w2r : w1r;
    const float* wi = sel ? w2i : w1i;
    for (int f = tid; f < 6144; f += 256){
      int i8 = f / 768; int rem = f % 768;
      int o = rem / 12, ky = rem % 12;
      long addr = (((long)l*64 + ig*8 + i8)*64 + o)*144 + kx*12 + ky;
      sr[(i8*64 + o)*13 + ky] = wr[addr];
      si[(i8*64 + o)*13 + ky] = wi[addr];
    }
    __syncthreads();
    int j = sel ? (kx + 12) : kx;
    for (int f = tid; f < 6144; f += 256){
      int o = f & 63; int r = f >> 6;
      int ky = r % 12, i8 = r / 12;
      int sidx = (i8*64 + o)*13 + ky;
      wmix[(((long)l*288 + j*12 + ky))*4096 + (ig*8 + i8)*64 + o] =
          make_float2(sr[sidx], si[sidx]);
    }
  }
}

// ---- ext MLP + gate + encoder fused: writes x[b,h,w,c] f16 directly --------
__global__ __launch_bounds__(256) void k_gx(const float* __restrict__ ext,
      const float* __restrict__ day_emb, const float* __restrict__ hour_emb,
      const float* __restrict__ e1_w, const float* __restrict__ e1_b,
      const float* __restrict__ e2_w, const float* __restrict__ e2_b,
      const float* __restrict__ inp, const float* __restrict__ enc_w,
      const float* __restrict__ enc_b, f16_t* __restrict__ x){
  int b = blockIdx.y;
  int hw = blockIdx.x*256 + threadIdx.x;
  __shared__ float s[64];
  __shared__ float ew[320];
  __shared__ float eb[64];
  if (threadIdx.x < 64){
    int j = threadIdx.x;
    const float* e = ext + b*6;
    float emb[6];
    emb[0] = e[0];
    int d  = (int)e[2];
    emb[1] = day_emb[d*2];  emb[2] = day_emb[d*2+1];
    int hr = (int)e[3];
    emb[3] = hour_emb[hr*3]; emb[4] = hour_emb[hr*3+1]; emb[5] = hour_emb[hr*3+2];
    float acc = e1_b[j];
    #pragma unroll
    for (int k = 0; k < 6; k++) acc += emb[k]*e1_w[j*6+k];
    s[j] = gelu_f(acc);
    eb[j] = enc_b[j];
  }
  for (int f = threadIdx.x; f < 320; f += 256) ew[f] = enc_w[f];
  __syncthreads();
  const float4* wrow = (const float4*)(e2_w + (long)hw*64);
  float acc = e2_b[hw];
  #pragma unroll
  for (int k = 0; k < 16; k++){
    float4 v = wrow[k];
    acc += v.x*s[4*k] + v.y*s[4*k+1] + v.z*s[4*k+2] + v.w*s[4*k+3];
  }
  float gv = gelu_f(acc);
  long pix = (long)b*(HH_*WW_) + hw;
  float4 ip = *(const float4*)(inp + pix*4);
  f16_t* xp = x + pix*64;
  #pragma unroll
  for (int c8 = 0; c8 < 8; c8++){
    half8 hv;
    #pragma unroll
    for (int e = 0; e < 8; e++){
      int c = c8*8 + e;
      const float* wr2 = ew + c*5;
      hv[e] = (f16_t)(eb[c] + ip.x*wr2[0] + ip.y*wr2[1] + ip.z*wr2[2]
                      + ip.w*wr2[3] + gv*wr2[4]);
    }
    *(half8*)(xp + c8*8) = hv;
  }
}

// ---------------- forward DFT along w (layer 0 only): fp0 -------------------
__global__ __launch_bounds__(256) void k_dft_w(const f16_t* __restrict__ x,
      const float4* __restrict__ twf4, float2* __restrict__ fft1){
  __shared__ float4 tw[1536];                      // [w][6]
  for (int f = threadIdx.x; f < 1536; f += 256) tw[f] = twf4[f];
  __syncthreads();
  int wave = threadIdx.x >> 6, lane = threadIdx.x & 63;
  long row = (long)blockIdx.x*4 + wave;            // b*H + h
  const f16_t* xr = x + row*16384 + lane;
  float ar[12], ai[12];
  #pragma unroll
  for (int k = 0; k < 12; k++){ ar[k] = 0.f; ai[k] = 0.f; }
  for (int w = 0; w < 256; w++){
    float xv = (float)xr[(long)w*64];
    const float4* t = &tw[w*6];
    #pragma unroll
    for (int k = 0; k < 6; k++){
      float4 tv = t[k];
      ar[2*k]   += xv*tv.x;  ai[2*k]   += xv*tv.y;
      ar[2*k+1] += xv*tv.z;  ai[2*k+1] += xv*tv.w;
    }
  }
  float2* op = fft1 + row*768 + lane;
  #pragma unroll
  for (int ky = 0; ky < 12; ky++) op[ky*64] = make_float2(ar[ky], ai[ky]);
}

// ---- FUSED spectral chain: dft_h + mode-mix + ifft_h, block=(b,ky) ---------
__global__ __launch_bounds__(256) void k_spec(const float2* __restrict__ s0,
      const float2* __restrict__ s1, int dual, const float2* __restrict__ thf_g,
      const float2* __restrict__ thi_g, const float2* __restrict__ wmix,
      int layer, float2* __restrict__ zi){
  __shared__ __align__(16) char sm[40960];
  float2* th  = (float2*)sm;            // 3072 f2: thf (A) then thi (C)
  float2* xch = (float2*)(sm + 24576);  // 2048 f2 staging (A)
  float2* mixL= (float2*)(sm + 24576);  // [24 j][64 o] (B->C), aliases xch
  int tid = threadIdx.x;
  int b = blockIdx.x / 12, ky = blockIdx.x % 12;
  int wv = tid >> 6, lane = tid & 63;
  for (int f = tid; f < 3072; f += 256) th[f] = thf_g[f];
  // Stage A: h-DFT. acc[q] = xft[j=q*4+wv][c=lane]
  float2 acc[6];
  #pragma unroll
  for (int q = 0; q < 6; q++) acc[q] = make_float2(0.f, 0.f);
  long base = (long)b*98304 + ky*64;
  for (int ch = 0; ch < 4; ch++){
    __syncthreads();
    for (int f = tid; f < 2048; f += 256){
      int hh = f >> 6, c = f & 63;
      long idx = base + (long)(ch*32 + hh)*768 + c;
      float2 v = s0[idx];
      if (dual){ float2 u = s1[idx]; v.x += u.x; v.y += u.y; }
      xch[f] = v;
    }
    __syncthreads();
    for (int hh = 0; hh < 32; hh++){
      float2 v = xch[hh*64 + lane];
      int hg = ch*32 + hh;
      #pragma unroll
      for (int q = 0; q < 6; q++){
        float2 t = th[hg*24 + q*4 + wv];
        acc[q].x += t.x*v.x - t.y*v.y;
        acc[q].y += t.x*v.y + t.y*v.x;
      }
    }
  }
  __syncthreads();                      // A done: xch & thf dead after here
  for (int f = tid; f < 3072; f += 256) th[f] = thi_g[f];   // stage thi
  // Stage B: mode-mix, register-resident via shfl; weights streamed from L2
  float2 mout[6];
  #pragma unroll
  for (int q = 0; q < 6; q++){
    int j = q*4 + wv;
    const float2* wj = wmix + (((long)layer*288 + j*12 + ky))*4096;
    float re = 0.f, im = 0.f;
    #pragma unroll 8
    for (int i = 0; i < 64; i++){
      float vr = __shfl(acc[q].x, i);
      float vi = __shfl(acc[q].y, i);
      float2 ww = wj[i*64 + lane];
      re += vr*ww.x - vi*ww.y;
      im += vr*ww.y + vi*ww.x;
    }
    mout[q] = make_float2(re, im);
  }
  #pragma unroll
  for (int q = 0; q < 6; q++) mixL[(q*4 + wv)*64 + lane] = mout[q];
  __syncthreads();                      // mixL + thi ready
  // Stage C: inverse h-DFT
  float2 cr[24];
  #pragma unroll
  for (int j = 0; j < 24; j++) cr[j] = mixL[j*64 + lane];
  for (int qq = 0; qq < 32; qq++){
    int h = qq*4 + wv;
    float re = 0.f, im = 0.f;
    #pragma unroll
    for (int j = 0; j < 24; j++){
      float2 t = th[h*24 + j];
      re += t.x*cr[j].x - t.y*cr[j].y;
      im += t.x*cr[j].y + t.y*cr[j].x;
    }
    zi[((long)b*128 + h)*768 + ky*64 + lane] = make_float2(re, im);
  }
}

// ------- MFMA: inverse-w + skip + bias + (gelu), in place on x,
//         fused next-layer partial w-DFT (LDS-staged twiddles) ---------------
__global__ __launch_bounds__(256) void k_iw_mfma(f16_t* __restrict__ x,
      const float2* __restrict__ zi, const float* __restrict__ ws_w,
      const float* __restrict__ ws_b, const f16_t* __restrict__ twzh,
      const float4* __restrict__ twf4g, float2* __restrict__ fp0,
      float2* __restrict__ fp1, int layer, int act, int dodft){
  __shared__ __align__(16) char sm[52736];
  f16_t* A  = (f16_t*)sm;                   // [128][136] phase1
  f16_t* Bm = (f16_t*)(sm + 34816);         // [64][136]  phase1
  float* sb = (float*)(sm + 52224);         // [64]
  f16_t* Ob  = (f16_t*)sm;                  // [128][72]  phase2
  float2* ps = (float2*)(sm + 18432);       // 2 x 768 float2
  float4* twl= (float4*)(sm + 30720);       // [128][6] float4
  int tid = threadIdx.x;
  int blk = blockIdx.x;
  int half = blk & 1;
  long bh = blk >> 1;                       // b*128 + h
  int w0 = half*128;
  const f16_t* xrow = x + (bh*256 + w0)*64;
  for (int f = tid; f < 1024; f += 256){    // x part, 16B copies
    int px = f >> 3, c8 = (f & 7)*8;
    *(float4*)((char*)A + (px*136 + c8)*2) = *(const float4*)(xrow + px*64 + c8);
  }
  for (int f = tid; f < 3072; f += 256){    // twz part (duplicated hi/lo)
    int px = f/24, k = f%24;
    f16_t v = twzh[(w0+px)*32 + k];
    A[px*136 + 64 + k] = v;
    A[px*136 + 88 + k] = v;
  }
  for (int f = tid; f < 3072; f += 256){    // A zero pad k=112..135
    int px = f/24, k = f%24;
    A[px*136 + 112 + k] = (f16_t)0.f;
  }
  const float* wsl = ws_w + (long)layer*4096;
  for (int f = tid; f < 1024; f += 256){    // B ws part
    int o = f >> 4, c4 = f & 15;
    float4 v = *(const float4*)(wsl + o*64 + c4*4);
    f16_t* d = Bm + o*136 + c4*4;
    d[0]=(f16_t)v.x; d[1]=(f16_t)v.y; d[2]=(f16_t)v.z; d[3]=(f16_t)v.w;
  }
  const float2* zrow = zi + bh*768;
  for (int f = tid; f < 768; f += 256){     // B z hi/lo
    int o = f & 63, ky = f >> 6;
    float2 v = zrow[ky*64 + o];
    f16_t hr = (f16_t)v.x; f16_t hi_ = (f16_t)v.y;
    Bm[o*136 + 64 + ky] = hr;
    Bm[o*136 + 76 + ky] = hi_;
    Bm[o*136 + 88 + ky] = (f16_t)(v.x - (float)hr);
    Bm[o*136 +100 + ky] = (f16_t)(v.y - (float)hi_);
  }
  for (int f = tid; f < 1536; f += 256){    // B zero pad
    int o = f/24, k = f%24;
    Bm[o*136 + 112 + k] = (f16_t)0.f;
  }
  if (tid < 64) sb[tid] = ws_b[layer*64 + tid];
  __syncthreads();
  int lane = tid & 63, wv = tid >> 6;
  int n15 = lane & 15, quad = lane >> 4;
  int n = wv*16 + n15;
  half8 bfr[4];
  #pragma unroll
  for (int kc = 0; kc < 4; kc++)
    bfr[kc] = *(const half8*)(Bm + n*136 + kc*32 + quad*8);
  floatx4 acc[8];
  #pragma unroll
  for (int mt = 0; mt < 8; mt++){
    floatx4 c = {0.f,0.f,0.f,0.f};
    #pragma unroll
    for (int kc = 0; kc < 4; kc++){
      half8 a = *(const half8*)(A + (mt*16 + n15)*136 + kc*32 + quad*8);
      c = __builtin_amdgcn_mfma_f32_16x16x32_f16(a, bfr[kc], c, 0, 0, 0);
    }
    acc[mt] = c;
  }
  float bias = sb[n];
  __syncthreads();                           // A/Bm dead -> Ob, ps, twl
  #pragma unroll
  for (int mt = 0; mt < 8; mt++){
    #pragma unroll
    for (int r = 0; r < 4; r++){
      int m = mt*16 + quad*4 + r;
      float v = acc[mt][r] + bias;
      if (act) v = gelu_f(v);
      Ob[m*72 + n] = (f16_t)v;
    }
  }
  if (dodft){                                // stage this half-row's twiddles
    const float4* tsrc = twf4g + w0*6;
    for (int f = tid; f < 768; f += 256) twl[f] = tsrc[f];
  }
  __syncthreads();
  f16_t* xo = x + (bh*256 + w0)*64;
  for (int f = tid; f < 1024; f += 256){     // vectorized write-back
    int px = f >> 3, c8 = (f & 7)*8;
    *(float4*)(xo + px*64 + c8) = *(const float4*)((char*)Ob + (px*72 + c8)*2);
  }
  if (dodft){                                // partial w-DFT of this half-row
    int wl0 = wv*32;
    float ar[12], ai[12];
    #pragma unroll
    for (int k = 0; k < 12; k++){ ar[k] = 0.f; ai[k] = 0.f; }
    for (int i2 = 0; i2 < 32; i2++){
      int wl = wl0 + i2;
      float xv = (float)Ob[wl*72 + lane];
      const float4* t = &twl[wl*6];
      #pragma unroll
      for (int k = 0; k < 6; k++){
        float4 tv = t[k];
        ar[2*k]   += xv*tv.x;  ai[2*k]   += xv*tv.y;
        ar[2*k+1] += xv*tv.z;  ai[2*k+1] += xv*tv.w;
      }
    }
    if (wv < 2){
      #pragma unroll
      for (int k = 0; k < 12; k++)
        ps[wv*768 + k*64 + lane] = make_float2(ar[k], ai[k]);
    }
    __syncthreads();
    if (wv >= 2){
      #pragma unroll
      for (int k = 0; k < 12; k++){
        int idx = (wv-2)*768 + k*64 + lane;
        float2 v = ps[idx];
        ps[idx] = make_float2(v.x + ar[k], v.y + ai[k]);
      }
    }
    __syncthreads();
    float2* dst = half ? fp1 : fp0;
    for (int f = tid; f < 768; f += 256){
      float2 a0 = ps[f], a1 = ps[768 + f];
      dst[bh*768 + f] = make_float2(a0.x + a1.x, a0.y + a1.y);
    }
  }
}

// ------- MFMA conv 3x3 (per-batch weights) + gelu + head, fused; 64-px tiles -
__global__ __launch_bounds__(256) void k_conv_head(const f16_t* __restrict__ x,
      const float* __restrict__ ext, const f16_t* __restrict__ wT,
      const float* __restrict__ tb, const f16_t* __restrict__ f1T,
      const float* __restrict__ f1_b, const f16_t* __restrict__ f2T,
      const float* __restrict__ f2_b, const f16_t* __restrict__ f3T,
      const float* __restrict__ f3_b, float* __restrict__ out){
  __shared__ __align__(16) char sm[37632];
  f16_t* hf   = (f16_t*)sm;                 // [64][72]
  f16_t* z1   = (f16_t*)(sm + 9216);        // [64][136]
  f16_t* z2   = (f16_t*)(sm + 26624);       // [64][72]
  float* tbs  = (float*)(sm + 35840);
  float* f1bs = (float*)(sm + 36096);
  float* f2bs = (float*)(sm + 36608);
  f16_t* f3s  = (f16_t*)(sm + 36864);
  float* f3bs = (float*)(sm + 37120);
  f16_t* xt   = (f16_t*)sm;                 // [3][66][72] (conv phase)

  int tid = threadIdx.x;
  int blk = blockIdx.x;
  int wc = blk & 3, h = (blk >> 2) & 127, b = blk >> 9;
  int w0 = wc*64;
  int t_idx = (int)ext[b*6+3] - 5;

  if (tid < 64) tbs[tid] = tb[t_idx*64 + tid];
  else if (tid < 192) f1bs[tid-64] = f1_b[tid-64];
  else f2bs[tid-192] = f2_b[tid-192];
  if (tid < 128) f3s[tid] = f3T[tid];
  if (tid < 2) f3bs[tid] = f3_b[tid];

  for (int f = tid; f < 3168; f += 256){    // xt: 3 rows x 66 px x 64 c
    int c4 = f & 15, r = f >> 4;
    int dy = r/66, pxl = r%66;
    int hh = h - 1 + dy, wg = w0 - 1 + pxl;
    ushort4 v = {0,0,0,0};
    if (hh >= 0 && hh < HH_ && wg >= 0 && wg < WW_)
      v = *(const ushort4*)(x + (((long)b*HH_ + hh)*WW_ + wg)*64 + c4*4);
    *(ushort4*)((unsigned short*)xt + (dy*66 + pxl)*72 + c4*4) = v;
  }
  __syncthreads();

  int lane = tid & 63, wv = tid >> 6;
  int n15 = lane & 15, quad = lane >> 4;

  floatx4 acc[4];
  #pragma unroll
  for (int mt = 0; mt < 4; mt++) acc[mt] = (floatx4){0.f,0.f,0.f,0.f};
  const f16_t* wTt = wT + (long)t_idx*36864;
  for (int tap = 0; tap < 9; tap++){
    int dy = tap/3, dx = tap%3;
    const f16_t* wrow = wTt + (tap*64 + wv*16 + n15)*64;
    #pragma unroll
    for (int kc = 0; kc < 2; kc++){
      half8 bfrag = *(const half8*)(wrow + kc*32 + quad*8);
      #pragma unroll
      for (int mt = 0; mt < 4; mt++){
        int p = mt*16 + n15 + dx;
        half8 a = *(const half8*)(xt + (dy*66 + p)*72 + kc*32 + quad*8);
        acc[mt] = __builtin_amdgcn_mfma_f32_16x16x32_f16(a, bfrag, acc[mt], 0,0,0);
      }
    }
  }
  __syncthreads();                           // xt dead
  {
    int n = wv*16 + n15;
    float bias = tbs[n];
    #pragma unroll
    for (int mt = 0; mt < 4; mt++){
      #pragma unroll
      for (int r = 0; r < 4; r++){
        int m = mt*16 + quad*4 + r;
        hf[m*72 + n] = (f16_t)gelu_f(acc[mt][r] + bias);
      }
    }
  }
  __syncthreads();
  // z1 = gelu(hf . f1^T + f1_b): M=64 N=128 K=64
  #pragma unroll
  for (int nt = 0; nt < 2; nt++){
    int n = wv*32 + nt*16 + n15;
    float bias = f1bs[n];
    half8 bf0 = *(const half8*)(f1T + n*64 + quad*8);
    half8 bf1 = *(const half8*)(f1T + n*64 + 32 + quad*8);
    #pragma unroll
    for (int mt = 0; mt < 4; mt++){
      floatx4 c = {0.f,0.f,0.f,0.f};
      half8 a0 = *(const half8*)(hf + (mt*16 + n15)*72 + quad*8);
      half8 a1 = *(const half8*)(hf + (mt*16 + n15)*72 + 32 + quad*8);
      c = __builtin_amdgcn_mfma_f32_16x16x32_f16(a0, bf0, c, 0,0,0);
      c = __builtin_amdgcn_mfma_f32_16x16x32_f16(a1, bf1, c, 0,0,0);
      #pragma unroll
      for (int r = 0; r < 4; r++){
        int m = mt*16 + quad*4 + r;
        z1[m*136 + n] = (f16_t)gelu_f(c[r] + bias);
      }
    }
  }
  __syncthreads();
  // z2 = gelu(z1 . f2^T + f2_b): M=64 N=64 K=128
  {
    int n = wv*16 + n15;
    float bias = f2bs[n];
    half8 bf[4];
    #pragma unroll
    for (int kc = 0; kc < 4; kc++)
      bf[kc] = *(const half8*)(f2T + n*128 + kc*32 + quad*8);
    #pragma unroll
    for (int mt = 0; mt < 4; mt++){
      floatx4 c = {0.f,0.f,0.f,0.f};
      #pragma unroll
      for (int kc = 0; kc < 4; kc++){
        half8 a = *(const half8*)(z1 + (mt*16 + n15)*136 + kc*32 + quad*8);
        c = __builtin_amdgcn_mfma_f32_16x16x32_f16(a, bf[kc], c, 0,0,0);
      }
      #pragma unroll
      for (int r = 0; r < 4; r++){
        int m = mt*16 + quad*4 + r;
        z2[m*72 + n] = (f16_t)gelu_f(c[r] + bias);
      }
    }
  }
  __syncthreads();
  // f3: out[px][0..1]
  if (tid < 128){
    int px = tid >> 1, oo = tid & 1;
    const f16_t* zr = z2 + px*72;
    const f16_t* fr = f3s + oo*64;
    float a = f3bs[oo];
    #pragma unroll
    for (int g = 0; g < 8; g++){
      half8 zv = *(const half8*)(zr + g*8);
      half8 wv2 = *(const half8*)(fr + g*8);
      #pragma unroll
      for (int q = 0; q < 8; q++) a += (float)zv[q]*(float)wv2[q];
    }
    out[(((long)b*HH_ + h)*WW_ + w0 + px)*2 + oo] = a;
  }
}

extern "C" void kernel_launch(void* const* d_in, const int* in_sizes, int n_in,
                              void* d_out, int out_size, void* d_ws, size_t ws_size,
                              hipStream_t stream){
  const float* inp     = (const float*)d_in[0];
  const float* ext     = (const float*)d_in[1];
  const float* enc_w   = (const float*)d_in[2];
  const float* enc_b   = (const float*)d_in[3];
  const float* w1r     = (const float*)d_in[4];
  const float* w1i     = (const float*)d_in[5];
  const float* w2r     = (const float*)d_in[6];
  const float* w2i     = (const float*)d_in[7];
  const float* ws_w    = (const float*)d_in[8];
  const float* ws_b    = (const float*)d_in[9];
  const float* day_emb = (const float*)d_in[10];
  const float* hour_emb= (const float*)d_in[11];
  const float* e1_w    = (const float*)d_in[12];
  const float* e1_b    = (const float*)d_in[13];
  const float* e2_w    = (const float*)d_in[14];
  const float* e2_b    = (const float*)d_in[15];
  const float* tw      = (const float*)d_in[16];
  const float* tb      = (const float*)d_in[17];
  const float* f1_w    = (const float*)d_in[18];
  const float* f1_b    = (const float*)d_in[19];
  const float* f2_w    = (const float*)d_in[20];
  const float* f2_b    = (const float*)d_in[21];
  const float* f3_w    = (const float*)d_in[22];
  const float* f3_b    = (const float*)d_in[23];
  float* outp = (float*)d_out;

  const size_t need = 248619264;
  if (ws_size < need){
    k_diag<<<dim3(1), dim3(64), 0, stream>>>(outp, (float)(ws_size >> 20));
    return;
  }
  char* p = (char*)d_ws;
  f16_t*  x    = (f16_t*)(p);                    // 134217728 B
  float2* fp0  = (float2*)(p + 134217728);       // 25165824 B
  float2* fp1  = (float2*)(p + 159383552);       // 25165824 B
  float2* zi   = (float2*)(p + 184549376);       // 25165824 B
  float2* twf  = (float2*)(p + 209715200);       // 24576 B
  float2* thf  = (float2*)(p + 209739776);       // 24576 B
  float2* thi  = (float2*)(p + 209764352);       // 24576 B
  f16_t*  twzh = (f16_t*)(p + 209788928);        // 16384 B
  f16_t*  wT   = (f16_t*)(p + 209805312);        // 1032192 B
  f16_t*  f1T  = (f16_t*)(p + 210837504);        // 16384 B
  f16_t*  f2T  = (f16_t*)(p + 210853888);        // 16384 B
  f16_t*  f3T  = (f16_t*)(p + 210870272);        // 256 B
  float2* wmix = (float2*)(p + 210870528);       // 37748736 B

  k_prep<<<dim3(937), dim3(256), 0, stream>>>(twf, thf, thi, twzh,
      f1_w, f2_w, f3_w, f1T, f2T, f3T, tw, wT, w1r, w1i, w2r, w2i, wmix);
  k_gx<<<dim3(128, 32), dim3(256), 0, stream>>>(ext, day_emb, hour_emb,
      e1_w, e1_b, e2_w, e2_b, inp, enc_w, enc_b, x);
  k_dft_w<<<dim3(1024), dim3(256), 0, stream>>>(x, (const float4*)twf, fp0);
  for (int l = 0; l < 4; l++){
    k_spec<<<dim3(384), dim3(256), 0, stream>>>(fp0, fp1, (l > 0) ? 1 : 0,
                                                thf, thi, wmix, l, zi);
    k_iw_mfma<<<dim3(8192), dim3(256), 0, stream>>>(x, zi, ws_w, ws_b, twzh,
                       (const float4*)twf, fp0, fp1,
                       l, (l < 3) ? 1 : 0, (l < 3) ? 1 : 0);
  }
  k_conv_head<<<dim3(16384), dim3(256), 0, stream>>>(x, ext, wT, tb,
                     f1T, f1_b, f2T, f2_b, f3T, f3_b, outp);
}

// Round 11
// 1427.947 us; speedup vs baseline: 1.1343x; 1.0555x over previous
//
#include <hip/hip_runtime.h>
#include <math.h>

#define BB 32
#define HH_ 128
#define WW_ 256

typedef _Float16 f16_t;
typedef _Float16 half8 __attribute__((ext_vector_type(8)));
typedef _Float16 half4 __attribute__((ext_vector_type(4)));
typedef float floatx4 __attribute__((ext_vector_type(4)));

__device__ __forceinline__ float gelu_f(float v){
  return 0.5f * v * (1.0f + erff(v * 0.70710678118654752f));
}

__global__ void k_diag(float* out, float v){ out[threadIdx.x] = v; }

// ---- merged prep: [0,113) tables+head-f16; [113,169) wprep;
//      [169,937) mixprep; [937,1001) twA (forward-dft MFMA A-matrix, hi/lo) --
__global__ __launch_bounds__(256) void k_prep(
      float2* twf, float2* thf, float2* thi, f16_t* twzh,
      const float* __restrict__ f1_w, const float* __restrict__ f2_w,
      const float* __restrict__ f3_w, f16_t* f1T, f16_t* f2T, f16_t* f3T,
      const float* __restrict__ tw, f16_t* __restrict__ wT,
      const float* __restrict__ w1r, const float* __restrict__ w1i,
      const float* __restrict__ w2r, const float* __restrict__ w2i,
      float2* __restrict__ wmix, f16_t* __restrict__ twA){
  __shared__ __align__(16) char smp[53248];
  const double PI2 = 6.283185307179586476925286766559;
  int blk = blockIdx.x, tid = threadIdx.x;
  if (blk < 113){
    int t = blk*256 + tid;
    if (t < 3072){                       // forward w-DFT: [w][ky]
      int w = t/12, ky = t%12;
      double a = -PI2 * (double)(w*ky) / 256.0;
      twf[t] = make_float2((float)cos(a), (float)sin(a));
    } else if (t < 6144){                // forward h-DFT: [h][j]
      int f = t-3072; int h = f/24, j = f%24;
      int kx = (j<12)? j : j+104;
      double a = -PI2 * (double)(h*kx) / 128.0;
      thf[f] = make_float2((float)cos(a), (float)sin(a));
    } else if (t < 9216){                // inverse h (includes 1/128)
      int f = t-6144; int h = f/24, j = f%24;
      int kx = (j<12)? j : j+104;
      double a = PI2 * (double)(h*kx) / 128.0;
      thi[f] = make_float2((float)(cos(a)/128.0), (float)(sin(a)/128.0));
    } else if (t < 12288){               // inverse w (c2r) coefs, f16
      int f = t-9216; int w = f/12, ky = f%12;
      double a = PI2 * (double)(w*ky) / 256.0;
      double s = (ky==0)? 1.0 : 2.0;
      twzh[w*32 + ky]      = (f16_t)( s*cos(a)/256.0);
      twzh[w*32 + 12 + ky] = (f16_t)(-s*sin(a)/256.0);
      if (ky < 8) twzh[w*32 + 24 + ky] = (f16_t)0.f;
    } else {
      int t2 = t - 12288;                // head weights -> f16
      if (t2 < 8192) f1T[t2] = (f16_t)f1_w[t2];
      else if (t2 < 16384) f2T[t2-8192] = (f16_t)f2_w[t2-8192];
      else if (t2 < 16512) f3T[t2-16384] = (f16_t)f3_w[t2-16384];
    }
  } else if (blk < 169){                 // conv weight transpose via LDS
    float* s = (float*)smp;              // [o16][c][tap]
    int b2 = blk - 113;
    int og = b2 & 3, tt = b2 >> 2;
    const float* src = tw + (long)tt*36864 + og*9216;
    for (int f = tid; f < 9216; f += 256) s[f] = src[f];
    __syncthreads();
    for (int f = tid; f < 9216; f += 256){
      int c = f & 63; int r = f >> 6;
      int o16 = r % 16, tap = r / 16;
      float v = s[(o16*64 + c)*9 + tap];
      wT[(((long)tt*9 + tap)*64 + og*16 + o16)*64 + c] = (f16_t)v;
    }
  } else if (blk < 937){                 // spectral weight transpose via LDS
    float* sr = (float*)smp;             // 6656 f
    float* si = (float*)(smp + 26624);   // 6656 f
    int b2 = blk - 169;                  // < 768
    int ig  = b2 & 7;
    int kx  = (b2 >> 3) % 12;
    int sel = (b2 / 96) & 1;
    int l   = b2 / 192;
    const float* wr = sel ? w2r : w1r;
    const float* wi = sel ? w2i : w1i;
    for (int f = tid; f < 6144; f += 256){
      int i8 = f / 768; int rem = f % 768;
      int o = rem / 12, ky = rem % 12;
      long addr = (((long)l*64 + ig*8 + i8)*64 + o)*144 + kx*12 + ky;
      sr[(i8*64 + o)*13 + ky] = wr[addr];
      si[(i8*64 + o)*13 + ky] = wi[addr];
    }
    __syncthreads();
    int j = sel ? (kx + 12) : kx;
    for (int f = tid; f < 6144; f += 256){
      int o = f & 63; int r = f >> 6;
      int ky = r % 12, i8 = r / 12;
      int sidx = (i8*64 + o)*13 + ky;
      wmix[(((long)l*288 + j*12 + ky))*4096 + (ig*8 + i8)*64 + o] =
          make_float2(sr[sidx], si[sidx]);
    }
  } else {                               // twA[half][hl][32 m][128 k] f16
    int t = (blk - 937)*256 + tid;       // < 16384
    int halfi = t >> 13, r = t & 8191;
    int hl = r >> 12, r2 = r & 4095;
    int m = r2 >> 7, k = r2 & 127;
    f16_t v = (f16_t)0.f;
    if (m < 24){
      int ky = m >> 1, ri = m & 1;
      int w = halfi*128 + k;
      double a = -PI2 * (double)(w*ky) / 256.0;
      float t32 = (float)(ri ? sin(a) : cos(a));
      f16_t hi = (f16_t)t32;
      v = hl ? (f16_t)(t32 - (float)hi) : hi;
    }
    twA[t] = v;
  }
}

// ---- ext MLP + gate + encoder fused: writes x[b,h,w,c] f16 directly --------
__global__ __launch_bounds__(256) void k_gx(const float* __restrict__ ext,
      const float* __restrict__ day_emb, const float* __restrict__ hour_emb,
      const float* __restrict__ e1_w, const float* __restrict__ e1_b,
      const float* __restrict__ e2_w, const float* __restrict__ e2_b,
      const float* __restrict__ inp, const float* __restrict__ enc_w,
      const float* __restrict__ enc_b, f16_t* __restrict__ x){
  int b = blockIdx.y;
  int hw = blockIdx.x*256 + threadIdx.x;
  __shared__ float s[64];
  __shared__ float ew[320];
  __shared__ float eb[64];
  if (threadIdx.x < 64){
    int j = threadIdx.x;
    const float* e = ext + b*6;
    float emb[6];
    emb[0] = e[0];
    int d  = (int)e[2];
    emb[1] = day_emb[d*2];  emb[2] = day_emb[d*2+1];
    int hr = (int)e[3];
    emb[3] = hour_emb[hr*3]; emb[4] = hour_emb[hr*3+1]; emb[5] = hour_emb[hr*3+2];
    float acc = e1_b[j];
    #pragma unroll
    for (int k = 0; k < 6; k++) acc += emb[k]*e1_w[j*6+k];
    s[j] = gelu_f(acc);
    eb[j] = enc_b[j];
  }
  for (int f = threadIdx.x; f < 320; f += 256) ew[f] = enc_w[f];
  __syncthreads();
  const float4* wrow = (const float4*)(e2_w + (long)hw*64);
  float acc = e2_b[hw];
  #pragma unroll
  for (int k = 0; k < 16; k++){
    float4 v = wrow[k];
    acc += v.x*s[4*k] + v.y*s[4*k+1] + v.z*s[4*k+2] + v.w*s[4*k+3];
  }
  float gv = gelu_f(acc);
  long pix = (long)b*(HH_*WW_) + hw;
  float4 ip = *(const float4*)(inp + pix*4);
  f16_t* xp = x + pix*64;
  #pragma unroll
  for (int c8 = 0; c8 < 8; c8++){
    half8 hv;
    #pragma unroll
    for (int e = 0; e < 8; e++){
      int c = c8*8 + e;
      const float* wr2 = ew + c*5;
      hv[e] = (f16_t)(eb[c] + ip.x*wr2[0] + ip.y*wr2[1] + ip.z*wr2[2]
                      + ip.w*wr2[3] + gv*wr2[4]);
    }
    *(half8*)(xp + c8*8) = hv;
  }
}

// ---------------- forward DFT along w (layer 0 only): fp0 -------------------
__global__ __launch_bounds__(256) void k_dft_w(const f16_t* __restrict__ x,
      const float4* __restrict__ twf4, float2* __restrict__ fft1){
  __shared__ float4 tw[1536];                      // [w][6]
  for (int f = threadIdx.x; f < 1536; f += 256) tw[f] = twf4[f];
  __syncthreads();
  int wave = threadIdx.x >> 6, lane = threadIdx.x & 63;
  long row = (long)blockIdx.x*4 + wave;            // b*H + h
  const f16_t* xr = x + row*16384 + lane;
  float ar[12], ai[12];
  #pragma unroll
  for (int k = 0; k < 12; k++){ ar[k] = 0.f; ai[k] = 0.f; }
  for (int w = 0; w < 256; w++){
    float xv = (float)xr[(long)w*64];
    const float4* t = &tw[w*6];
    #pragma unroll
    for (int k = 0; k < 6; k++){
      float4 tv = t[k];
      ar[2*k]   += xv*tv.x;  ai[2*k]   += xv*tv.y;
      ar[2*k+1] += xv*tv.z;  ai[2*k+1] += xv*tv.w;
    }
  }
  float2* op = fft1 + row*768 + lane;
  #pragma unroll
  for (int ky = 0; ky < 12; ky++) op[ky*64] = make_float2(ar[ky], ai[ky]);
}

// ---- FUSED spectral chain: dft_h + mode-mix + ifft_h, block=(b,ky) ---------
__global__ __launch_bounds__(256) void k_spec(const float2* __restrict__ s0,
      const float2* __restrict__ s1, int dual, const float2* __restrict__ thf_g,
      const float2* __restrict__ thi_g, const float2* __restrict__ wmix,
      int layer, float2* __restrict__ zi){
  __shared__ __align__(16) char sm[40960];
  float2* th  = (float2*)sm;            // 3072 f2: thf (A) then thi (C)
  float2* xch = (float2*)(sm + 24576);  // 2048 f2 staging (A)
  float2* mixL= (float2*)(sm + 24576);  // [24 j][64 o] (B->C), aliases xch
  int tid = threadIdx.x;
  int b = blockIdx.x / 12, ky = blockIdx.x % 12;
  int wv = tid >> 6, lane = tid & 63;
  for (int f = tid; f < 3072; f += 256) th[f] = thf_g[f];
  // Stage A: h-DFT. acc[q] = xft[j=q*4+wv][c=lane]
  float2 acc[6];
  #pragma unroll
  for (int q = 0; q < 6; q++) acc[q] = make_float2(0.f, 0.f);
  long base = (long)b*98304 + ky*64;
  for (int ch = 0; ch < 4; ch++){
    __syncthreads();
    for (int f = tid; f < 2048; f += 256){
      int hh = f >> 6, c = f & 63;
      long idx = base + (long)(ch*32 + hh)*768 + c;
      float2 v = s0[idx];
      if (dual){ float2 u = s1[idx]; v.x += u.x; v.y += u.y; }
      xch[f] = v;
    }
    __syncthreads();
    for (int hh = 0; hh < 32; hh++){
      float2 v = xch[hh*64 + lane];
      int hg = ch*32 + hh;
      #pragma unroll
      for (int q = 0; q < 6; q++){
        float2 t = th[hg*24 + q*4 + wv];
        acc[q].x += t.x*v.x - t.y*v.y;
        acc[q].y += t.x*v.y + t.y*v.x;
      }
    }
  }
  __syncthreads();                      // A done: xch & thf dead after here
  for (int f = tid; f < 3072; f += 256) th[f] = thi_g[f];   // stage thi
  // Stage B: mode-mix, register-resident via shfl
  float2 mout[6];
  #pragma unroll
  for (int q = 0; q < 6; q++){
    int j = q*4 + wv;
    const float2* wj = wmix + (((long)layer*288 + j*12 + ky))*4096;
    float re = 0.f, im = 0.f;
    #pragma unroll 8
    for (int i = 0; i < 64; i++){
      float vr = __shfl(acc[q].x, i);
      float vi = __shfl(acc[q].y, i);
      float2 ww = wj[i*64 + lane];
      re += vr*ww.x - vi*ww.y;
      im += vr*ww.y + vi*ww.x;
    }
    mout[q] = make_float2(re, im);
  }
  #pragma unroll
  for (int q = 0; q < 6; q++) mixL[(q*4 + wv)*64 + lane] = mout[q];
  __syncthreads();                      // mixL + thi ready
  // Stage C: inverse h-DFT
  float2 cr[24];
  #pragma unroll
  for (int j = 0; j < 24; j++) cr[j] = mixL[j*64 + lane];
  for (int qq = 0; qq < 32; qq++){
    int h = qq*4 + wv;
    float re = 0.f, im = 0.f;
    #pragma unroll
    for (int j = 0; j < 24; j++){
      float2 t = th[h*24 + j];
      re += t.x*cr[j].x - t.y*cr[j].y;
      im += t.x*cr[j].y + t.y*cr[j].x;
    }
    zi[((long)b*128 + h)*768 + ky*64 + lane] = make_float2(re, im);
  }
}

// ------- MFMA: inverse-w + skip + bias + (gelu), in place on x,
//         fused next-layer partial w-DFT via MFMA (twA hi/lo) ----------------
__global__ __launch_bounds__(256) void k_iw_mfma(f16_t* __restrict__ x,
      const float2* __restrict__ zi, const float* __restrict__ ws_w,
      const float* __restrict__ ws_b, const f16_t* __restrict__ twzh,
      const f16_t* __restrict__ twA, float2* __restrict__ fp0,
      float2* __restrict__ fp1, int layer, int act, int dodft){
  __shared__ __align__(16) char sm[52736];
  f16_t* A  = (f16_t*)sm;                   // [128][136] phase1
  f16_t* Bm = (f16_t*)(sm + 34816);         // [64][136]  phase1
  float* sb = (float*)(sm + 52224);         // [64]
  f16_t* Obt  = (f16_t*)sm;                 // [64 c][136 w-pad] phase2
  f16_t* twA_l= (f16_t*)(sm + 17408);       // [2 hl][32 m][136 k-pad]
  int tid = threadIdx.x;
  int blk = blockIdx.x;
  int half = blk & 1;
  long bh = blk >> 1;                       // b*128 + h
  int w0 = half*128;
  const f16_t* xrow = x + (bh*256 + w0)*64;
  for (int f = tid; f < 1024; f += 256){    // x part, 16B copies
    int px = f >> 3, c8 = (f & 7)*8;
    *(float4*)((char*)A + (px*136 + c8)*2) = *(const float4*)(xrow + px*64 + c8);
  }
  for (int f = tid; f < 3072; f += 256){    // twz part (duplicated hi/lo)
    int px = f/24, k = f%24;
    f16_t v = twzh[(w0+px)*32 + k];
    A[px*136 + 64 + k] = v;
    A[px*136 + 88 + k] = v;
  }
  for (int f = tid; f < 3072; f += 256){    // A zero pad k=112..135
    int px = f/24, k = f%24;
    A[px*136 + 112 + k] = (f16_t)0.f;
  }
  const float* wsl = ws_w + (long)layer*4096;
  for (int f = tid; f < 1024; f += 256){    // B ws part
    int o = f >> 4, c4 = f & 15;
    float4 v = *(const float4*)(wsl + o*64 + c4*4);
    f16_t* d = Bm + o*136 + c4*4;
    d[0]=(f16_t)v.x; d[1]=(f16_t)v.y; d[2]=(f16_t)v.z; d[3]=(f16_t)v.w;
  }
  const float2* zrow = zi + bh*768;
  for (int f = tid; f < 768; f += 256){     // B z hi/lo
    int o = f & 63, ky = f >> 6;
    float2 v = zrow[ky*64 + o];
    f16_t hr = (f16_t)v.x; f16_t hi_ = (f16_t)v.y;
    Bm[o*136 + 64 + ky] = hr;
    Bm[o*136 + 76 + ky] = hi_;
    Bm[o*136 + 88 + ky] = (f16_t)(v.x - (float)hr);
    Bm[o*136 +100 + ky] = (f16_t)(v.y - (float)hi_);
  }
  for (int f = tid; f < 1536; f += 256){    // B zero pad
    int o = f/24, k = f%24;
    Bm[o*136 + 112 + k] = (f16_t)0.f;
  }
  if (tid < 64) sb[tid] = ws_b[layer*64 + tid];
  __syncthreads();
  int lane = tid & 63, wv = tid >> 6;
  int n15 = lane & 15, quad = lane >> 4;
  int n = wv*16 + n15;
  half8 bfr[4];
  #pragma unroll
  for (int kc = 0; kc < 4; kc++)
    bfr[kc] = *(const half8*)(Bm + n*136 + kc*32 + quad*8);
  floatx4 acc[8];
  #pragma unroll
  for (int mt = 0; mt < 8; mt++){
    floatx4 c = {0.f,0.f,0.f,0.f};
    #pragma unroll
    for (int kc = 0; kc < 4; kc++){
      half8 a = *(const half8*)(A + (mt*16 + n15)*136 + kc*32 + quad*8);
      c = __builtin_amdgcn_mfma_f32_16x16x32_f16(a, bfr[kc], c, 0, 0, 0);
    }
    acc[mt] = c;
  }
  float bias = sb[n];
  __syncthreads();                           // A/Bm dead -> Obt, twA_l
  #pragma unroll
  for (int mt = 0; mt < 8; mt++){            // transposed epilogue: Obt[c][w]
    half4 hv;
    #pragma unroll
    for (int r = 0; r < 4; r++){
      float v = acc[mt][r] + bias;
      if (act) v = gelu_f(v);
      hv[r] = (f16_t)v;
    }
    *(half4*)(Obt + n*136 + mt*16 + quad*4) = hv;
  }
  if (dodft){                                // stage twA (this half), re-strided
    const f16_t* tsrc = twA + half*8192;
    for (int f = tid; f < 1024; f += 256){
      int hl = f >> 9, m = (f >> 4) & 31, kc8 = f & 15;
      *(float4*)(twA_l + hl*4352 + m*136 + kc8*8) = *(const float4*)(tsrc + f*8);
    }
  }
  __syncthreads();
  f16_t* xo = x + (bh*256 + w0)*64;
  for (int f = tid; f < 1024; f += 256){     // write-back x from Obt (transposed)
    int px = f >> 3, c8 = f & 7;
    half8 hv;
    #pragma unroll
    for (int e = 0; e < 8; e++) hv[e] = Obt[(c8*8 + e)*136 + px];
    *(half8*)(xo + px*64 + c8*8) = hv;
  }
  if (dodft){                                // partial w-DFT via MFMA
    half8 bfr2[4];
    #pragma unroll
    for (int ks = 0; ks < 4; ks++)
      bfr2[ks] = *(const half8*)(Obt + n*136 + ks*32 + quad*8);
    floatx4 dacc[2];
    dacc[0] = (floatx4){0.f,0.f,0.f,0.f};
    dacc[1] = (floatx4){0.f,0.f,0.f,0.f};
    #pragma unroll
    for (int hl = 0; hl < 2; hl++){
      #pragma unroll
      for (int mt = 0; mt < 2; mt++){
        #pragma unroll
        for (int ks = 0; ks < 4; ks++){
          half8 a = *(const half8*)(twA_l + hl*4352 + (mt*16 + n15)*136
                                    + ks*32 + quad*8);
          dacc[mt] = __builtin_amdgcn_mfma_f32_16x16x32_f16(a, bfr2[ks],
                                                            dacc[mt], 0,0,0);
        }
      }
    }
    float2* dst = half ? fp1 : fp0;
    #pragma unroll
    for (int mt = 0; mt < 2; mt++){
      int m0 = mt*16 + quad*4;
      if (m0 < 24){
        int ky0 = m0 >> 1;
        dst[bh*768 + ky0*64 + n]     = make_float2(dacc[mt][0], dacc[mt][1]);
        dst[bh*768 + (ky0+1)*64 + n] = make_float2(dacc[mt][2], dacc[mt][3]);
      }
    }
  }
}

// ------- MFMA conv 3x3 (per-batch weights) + gelu + head, fused; 64-px tiles -
__global__ __launch_bounds__(256) void k_conv_head(const f16_t* __restrict__ x,
      const float* __restrict__ ext, const f16_t* __restrict__ wT,
      const float* __restrict__ tb, const f16_t* __restrict__ f1T,
      const float* __restrict__ f1_b, const f16_t* __restrict__ f2T,
      const float* __restrict__ f2_b, const f16_t* __restrict__ f3T,
      const float* __restrict__ f3_b, float* __restrict__ out){
  __shared__ __align__(16) char sm[37632];
  f16_t* hf   = (f16_t*)sm;                 // [64][72]
  f16_t* z1   = (f16_t*)(sm + 9216);        // [64][136]
  f16_t* z2   = (f16_t*)(sm + 26624);       // [64][72]
  float* tbs  = (float*)(sm + 35840);
  float* f1bs = (float*)(sm + 36096);
  float* f2bs = (float*)(sm + 36608);
  f16_t* f3s  = (f16_t*)(sm + 36864);
  float* f3bs = (float*)(sm + 37120);
  f16_t* xt   = (f16_t*)sm;                 // [3][66][72] (conv phase)

  int tid = threadIdx.x;
  int blk = blockIdx.x;
  int wc = blk & 3, h = (blk >> 2) & 127, b = blk >> 9;
  int w0 = wc*64;
  int t_idx = (int)ext[b*6+3] - 5;

  if (tid < 64) tbs[tid] = tb[t_idx*64 + tid];
  else if (tid < 192) f1bs[tid-64] = f1_b[tid-64];
  else f2bs[tid-192] = f2_b[tid-192];
  if (tid < 128) f3s[tid] = f3T[tid];
  if (tid < 2) f3bs[tid] = f3_b[tid];

  for (int f = tid; f < 3168; f += 256){    // xt: 3 rows x 66 px x 64 c
    int c4 = f & 15, r = f >> 4;
    int dy = r/66, pxl = r%66;
    int hh = h - 1 + dy, wg = w0 - 1 + pxl;
    ushort4 v = {0,0,0,0};
    if (hh >= 0 && hh < HH_ && wg >= 0 && wg < WW_)
      v = *(const ushort4*)(x + (((long)b*HH_ + hh)*WW_ + wg)*64 + c4*4);
    *(ushort4*)((unsigned short*)xt + (dy*66 + pxl)*72 + c4*4) = v;
  }
  __syncthreads();

  int lane = tid & 63, wv = tid >> 6;
  int n15 = lane & 15, quad = lane >> 4;

  floatx4 acc[4];
  #pragma unroll
  for (int mt = 0; mt < 4; mt++) acc[mt] = (floatx4){0.f,0.f,0.f,0.f};
  const f16_t* wTt = wT + (long)t_idx*36864;
  for (int tap = 0; tap < 9; tap++){
    int dy = tap/3, dx = tap%3;
    const f16_t* wrow = wTt + (tap*64 + wv*16 + n15)*64;
    #pragma unroll
    for (int kc = 0; kc < 2; kc++){
      half8 bfrag = *(const half8*)(wrow + kc*32 + quad*8);
      #pragma unroll
      for (int mt = 0; mt < 4; mt++){
        int p = mt*16 + n15 + dx;
        half8 a = *(const half8*)(xt + (dy*66 + p)*72 + kc*32 + quad*8);
        acc[mt] = __builtin_amdgcn_mfma_f32_16x16x32_f16(a, bfrag, acc[mt], 0,0,0);
      }
    }
  }
  __syncthreads();                           // xt dead
  {
    int n = wv*16 + n15;
    float bias = tbs[n];
    #pragma unroll
    for (int mt = 0; mt < 4; mt++){
      #pragma unroll
      for (int r = 0; r < 4; r++){
        int m = mt*16 + quad*4 + r;
        hf[m*72 + n] = (f16_t)gelu_f(acc[mt][r] + bias);
      }
    }
  }
  __syncthreads();
  // z1 = gelu(hf . f1^T + f1_b): M=64 N=128 K=64
  #pragma unroll
  for (int nt = 0; nt < 2; nt++){
    int n = wv*32 + nt*16 + n15;
    float bias = f1bs[n];
    half8 bf0 = *(const half8*)(f1T + n*64 + quad*8);
    half8 bf1 = *(const half8*)(f1T + n*64 + 32 + quad*8);
    #pragma unroll
    for (int mt = 0; mt < 4; mt++){
      floatx4 c = {0.f,0.f,0.f,0.f};
      half8 a0 = *(const half8*)(hf + (mt*16 + n15)*72 + quad*8);
      half8 a1 = *(const half8*)(hf + (mt*16 + n15)*72 + 32 + quad*8);
      c = __builtin_amdgcn_mfma_f32_16x16x32_f16(a0, bf0, c, 0,0,0);
      c = __builtin_amdgcn_mfma_f32_16x16x32_f16(a1, bf1, c, 0,0,0);
      #pragma unroll
      for (int r = 0; r < 4; r++){
        int m = mt*16 + quad*4 + r;
        z1[m*136 + n] = (f16_t)gelu_f(c[r] + bias);
      }
    }
  }
  __syncthreads();
  // z2 = gelu(z1 . f2^T + f2_b): M=64 N=64 K=128
  {
    int n = wv*16 + n15;
    float bias = f2bs[n];
    half8 bf[4];
    #pragma unroll
    for (int kc = 0; kc < 4; kc++)
      bf[kc] = *(const half8*)(f2T + n*128 + kc*32 + quad*8);
    #pragma unroll
    for (int mt = 0; mt < 4; mt++){
      floatx4 c = {0.f,0.f,0.f,0.f};
      #pragma unroll
      for (int kc = 0; kc < 4; kc++){
        half8 a = *(const half8*)(z1 + (mt*16 + n15)*136 + kc*32 + quad*8);
        c = __builtin_amdgcn_mfma_f32_16x16x32_f16(a, bf[kc], c, 0,0,0);
      }
      #pragma unroll
      for (int r = 0; r < 4; r++){
        int m = mt*16 + quad*4 + r;
        z2[m*72 + n] = (f16_t)gelu_f(c[r] + bias);
      }
    }
  }
  __syncthreads();
  // f3: out[px][0..1]
  if (tid < 128){
    int px = tid >> 1, oo = tid & 1;
    const f16_t* zr = z2 + px*72;
    const f16_t* fr = f3s + oo*64;
    float a = f3bs[oo];
    #pragma unroll
    for (int g = 0; g < 8; g++){
      half8 zv = *(const half8*)(zr + g*8);
      half8 wv2 = *(const half8*)(fr + g*8);
      #pragma unroll
      for (int q = 0; q < 8; q++) a += (float)zv[q]*(float)wv2[q];
    }
    out[(((long)b*HH_ + h)*WW_ + w0 + px)*2 + oo] = a;
  }
}

extern "C" void kernel_launch(void* const* d_in, const int* in_sizes, int n_in,
                              void* d_out, int out_size, void* d_ws, size_t ws_size,
                              hipStream_t stream){
  const float* inp     = (const float*)d_in[0];
  const float* ext     = (const float*)d_in[1];
  const float* enc_w   = (const float*)d_in[2];
  const float* enc_b   = (const float*)d_in[3];
  const float* w1r     = (const float*)d_in[4];
  const float* w1i     = (const float*)d_in[5];
  const float* w2r     = (const float*)d_in[6];
  const float* w2i     = (const float*)d_in[7];
  const float* ws_w    = (const float*)d_in[8];
  const float* ws_b    = (const float*)d_in[9];
  const float* day_emb = (const float*)d_in[10];
  const float* hour_emb= (const float*)d_in[11];
  const float* e1_w    = (const float*)d_in[12];
  const float* e1_b    = (const float*)d_in[13];
  const float* e2_w    = (const float*)d_in[14];
  const float* e2_b    = (const float*)d_in[15];
  const float* tw      = (const float*)d_in[16];
  const float* tb      = (const float*)d_in[17];
  const float* f1_w    = (const float*)d_in[18];
  const float* f1_b    = (const float*)d_in[19];
  const float* f2_w    = (const float*)d_in[20];
  const float* f2_b    = (const float*)d_in[21];
  const float* f3_w    = (const float*)d_in[22];
  const float* f3_b    = (const float*)d_in[23];
  float* outp = (float*)d_out;

  const size_t need = 248652032;
  if (ws_size < need){
    k_diag<<<dim3(1), dim3(64), 0, stream>>>(outp, (float)(ws_size >> 20));
    return;
  }
  char* p = (char*)d_ws;
  f16_t*  x    = (f16_t*)(p);                    // 134217728 B
  float2* fp0  = (float2*)(p + 134217728);       // 25165824 B
  float2* fp1  = (float2*)(p + 159383552);       // 25165824 B
  float2* zi   = (float2*)(p + 184549376);       // 25165824 B
  float2* twf  = (float2*)(p + 209715200);       // 24576 B
  float2* thf  = (float2*)(p + 209739776);       // 24576 B
  float2* thi  = (float2*)(p + 209764352);       // 24576 B
  f16_t*  twzh = (f16_t*)(p + 209788928);        // 16384 B
  f16_t*  wT   = (f16_t*)(p + 209805312);        // 1032192 B
  f16_t*  f1T  = (f16_t*)(p + 210837504);        // 16384 B
  f16_t*  f2T  = (f16_t*)(p + 210853888);        // 16384 B
  f16_t*  f3T  = (f16_t*)(p + 210870272);        // 256 B
  float2* wmix = (float2*)(p + 210870528);       // 37748736 B
  f16_t*  twA  = (f16_t*)(p + 248619264);        // 32768 B

  k_prep<<<dim3(1001), dim3(256), 0, stream>>>(twf, thf, thi, twzh,
      f1_w, f2_w, f3_w, f1T, f2T, f3T, tw, wT, w1r, w1i, w2r, w2i, wmix, twA);
  k_gx<<<dim3(128, 32), dim3(256), 0, stream>>>(ext, day_emb, hour_emb,
      e1_w, e1_b, e2_w, e2_b, inp, enc_w, enc_b, x);
  k_dft_w<<<dim3(1024), dim3(256), 0, stream>>>(x, (const float4*)twf, fp0);
  for (int l = 0; l < 4; l++){
    k_spec<<<dim3(384), dim3(256), 0, stream>>>(fp0, fp1, (l > 0) ? 1 : 0,
                                                thf, thi, wmix, l, zi);
    k_iw_mfma<<<dim3(8192), dim3(256), 0, stream>>>(x, zi, ws_w, ws_b, twzh,
                       twA, fp0, fp1, l, (l < 3) ? 1 : 0, (l < 3) ? 1 : 0);
  }
  k_conv_head<<<dim3(16384), dim3(256), 0, stream>>>(x, ext, wT, tb,
                     f1T, f1_b, f2T, f2_b, f3T, f3_b, outp);
}

// Round 12
// 1404.208 us; speedup vs baseline: 1.1535x; 1.0169x over previous
//
#include <hip/hip_runtime.h>
#include <math.h>

#define BB 32
#define HH_ 128
#define WW_ 256

typedef _Float16 f16_t;
typedef _Float16 half8 __attribute__((ext_vector_type(8)));
typedef _Float16 half4 __attribute__((ext_vector_type(4)));
typedef float floatx4 __attribute__((ext_vector_type(4)));

__device__ __forceinline__ float gelu_f(float v){
  return 0.5f * v * (1.0f + erff(v * 0.70710678118654752f));
}

__global__ void k_diag(float* out, float v){ out[threadIdx.x] = v; }

// ---- merged prep: [0,113) tables+head-f16; [113,169) wprep;
//      [169,937) mixprep; [937,1001) twA (forward-dft MFMA A-matrix, hi/lo) --
__global__ __launch_bounds__(256) void k_prep(
      float2* twf, float2* thf, float2* thi, f16_t* twzh,
      const float* __restrict__ f1_w, const float* __restrict__ f2_w,
      const float* __restrict__ f3_w, f16_t* f1T, f16_t* f2T, f16_t* f3T,
      const float* __restrict__ tw, f16_t* __restrict__ wT,
      const float* __restrict__ w1r, const float* __restrict__ w1i,
      const float* __restrict__ w2r, const float* __restrict__ w2i,
      float2* __restrict__ wmix, f16_t* __restrict__ twA){
  __shared__ __align__(16) char smp[53248];
  const double PI2 = 6.283185307179586476925286766559;
  int blk = blockIdx.x, tid = threadIdx.x;
  if (blk < 113){
    int t = blk*256 + tid;
    if (t < 3072){                       // forward w-DFT: [w][ky]
      int w = t/12, ky = t%12;
      double a = -PI2 * (double)(w*ky) / 256.0;
      twf[t] = make_float2((float)cos(a), (float)sin(a));
    } else if (t < 6144){                // forward h-DFT: [h][j]
      int f = t-3072; int h = f/24, j = f%24;
      int kx = (j<12)? j : j+104;
      double a = -PI2 * (double)(h*kx) / 128.0;
      thf[f] = make_float2((float)cos(a), (float)sin(a));
    } else if (t < 9216){                // inverse h (includes 1/128)
      int f = t-6144; int h = f/24, j = f%24;
      int kx = (j<12)? j : j+104;
      double a = PI2 * (double)(h*kx) / 128.0;
      thi[f] = make_float2((float)(cos(a)/128.0), (float)(sin(a)/128.0));
    } else if (t < 12288){               // inverse w (c2r) coefs, f16
      int f = t-9216; int w = f/12, ky = f%12;
      double a = PI2 * (double)(w*ky) / 256.0;
      double s = (ky==0)? 1.0 : 2.0;
      twzh[w*32 + ky]      = (f16_t)( s*cos(a)/256.0);
      twzh[w*32 + 12 + ky] = (f16_t)(-s*sin(a)/256.0);
      if (ky < 8) twzh[w*32 + 24 + ky] = (f16_t)0.f;
    } else {
      int t2 = t - 12288;                // head weights -> f16
      if (t2 < 8192) f1T[t2] = (f16_t)f1_w[t2];
      else if (t2 < 16384) f2T[t2-8192] = (f16_t)f2_w[t2-8192];
      else if (t2 < 16512) f3T[t2-16384] = (f16_t)f3_w[t2-16384];
    }
  } else if (blk < 169){                 // conv weight transpose via LDS
    float* s = (float*)smp;              // [o16][c][tap]
    int b2 = blk - 113;
    int og = b2 & 3, tt = b2 >> 2;
    const float* src = tw + (long)tt*36864 + og*9216;
    for (int f = tid; f < 9216; f += 256) s[f] = src[f];
    __syncthreads();
    for (int f = tid; f < 9216; f += 256){
      int c = f & 63; int r = f >> 6;
      int o16 = r % 16, tap = r / 16;
      float v = s[(o16*64 + c)*9 + tap];
      wT[(((long)tt*9 + tap)*64 + og*16 + o16)*64 + c] = (f16_t)v;
    }
  } else if (blk < 937){                 // spectral weight transpose via LDS
    float* sr = (float*)smp;             // 6656 f
    float* si = (float*)(smp + 26624);   // 6656 f
    int b2 = blk - 169;                  // < 768
    int ig  = b2 & 7;
    int kx  = (b2 >> 3) % 12;
    int sel = (b2 / 96) & 1;
    int l   = b2 / 192;
    const float* wr = sel ? w2r : w1r;
    const float* wi = sel ? w2i : w1i;
    for (int f = tid; f < 6144; f += 256){
      int i8 = f / 768; int rem = f % 768;
      int o = rem / 12, ky = rem % 12;
      long addr = (((long)l*64 + ig*8 + i8)*64 + o)*144 + kx*12 + ky;
      sr[(i8*64 + o)*13 + ky] = wr[addr];
      si[(i8*64 + o)*13 + ky] = wi[addr];
    }
    __syncthreads();
    int j = sel ? (kx + 12) : kx;
    for (int f = tid; f < 6144; f += 256){
      int o = f & 63; int r = f >> 6;
      int ky = r % 12, i8 = r / 12;
      int sidx = (i8*64 + o)*13 + ky;
      wmix[(((long)l*288 + j*12 + ky))*4096 + (ig*8 + i8)*64 + o] =
          make_float2(sr[sidx], si[sidx]);
    }
  } else {                               // twA[half][hl][32 m][128 k] f16
    int t = (blk - 937)*256 + tid;       // < 16384
    int halfi = t >> 13, r = t & 8191;
    int hl = r >> 12, r2 = r & 4095;
    int m = r2 >> 7, k = r2 & 127;
    f16_t v = (f16_t)0.f;
    if (m < 24){
      int ky = m >> 1, ri = m & 1;
      int w = halfi*128 + k;
      double a = -PI2 * (double)(w*ky) / 256.0;
      float t32 = (float)(ri ? sin(a) : cos(a));
      f16_t hi = (f16_t)t32;
      v = hl ? (f16_t)(t32 - (float)hi) : hi;
    }
    twA[t] = v;
  }
}

// ---- ext MLP + gate + encoder fused: writes x[b,h,w,c] f16 directly --------
__global__ __launch_bounds__(256) void k_gx(const float* __restrict__ ext,
      const float* __restrict__ day_emb, const float* __restrict__ hour_emb,
      const float* __restrict__ e1_w, const float* __restrict__ e1_b,
      const float* __restrict__ e2_w, const float* __restrict__ e2_b,
      const float* __restrict__ inp, const float* __restrict__ enc_w,
      const float* __restrict__ enc_b, f16_t* __restrict__ x){
  int b = blockIdx.y;
  int hw = blockIdx.x*256 + threadIdx.x;
  __shared__ float s[64];
  __shared__ float ew[320];
  __shared__ float eb[64];
  if (threadIdx.x < 64){
    int j = threadIdx.x;
    const float* e = ext + b*6;
    float emb[6];
    emb[0] = e[0];
    int d  = (int)e[2];
    emb[1] = day_emb[d*2];  emb[2] = day_emb[d*2+1];
    int hr = (int)e[3];
    emb[3] = hour_emb[hr*3]; emb[4] = hour_emb[hr*3+1]; emb[5] = hour_emb[hr*3+2];
    float acc = e1_b[j];
    #pragma unroll
    for (int k = 0; k < 6; k++) acc += emb[k]*e1_w[j*6+k];
    s[j] = gelu_f(acc);
    eb[j] = enc_b[j];
  }
  for (int f = threadIdx.x; f < 320; f += 256) ew[f] = enc_w[f];
  __syncthreads();
  const float4* wrow = (const float4*)(e2_w + (long)hw*64);
  float acc = e2_b[hw];
  #pragma unroll
  for (int k = 0; k < 16; k++){
    float4 v = wrow[k];
    acc += v.x*s[4*k] + v.y*s[4*k+1] + v.z*s[4*k+2] + v.w*s[4*k+3];
  }
  float gv = gelu_f(acc);
  long pix = (long)b*(HH_*WW_) + hw;
  float4 ip = *(const float4*)(inp + pix*4);
  f16_t* xp = x + pix*64;
  #pragma unroll
  for (int c8 = 0; c8 < 8; c8++){
    half8 hv;
    #pragma unroll
    for (int e = 0; e < 8; e++){
      int c = c8*8 + e;
      const float* wr2 = ew + c*5;
      hv[e] = (f16_t)(eb[c] + ip.x*wr2[0] + ip.y*wr2[1] + ip.z*wr2[2]
                      + ip.w*wr2[3] + gv*wr2[4]);
    }
    *(half8*)(xp + c8*8) = hv;
  }
}

// ---------------- forward DFT along w (layer 0 only): fp0 -------------------
__global__ __launch_bounds__(256) void k_dft_w(const f16_t* __restrict__ x,
      const float4* __restrict__ twf4, float2* __restrict__ fft1){
  __shared__ float4 tw[1536];                      // [w][6]
  for (int f = threadIdx.x; f < 1536; f += 256) tw[f] = twf4[f];
  __syncthreads();
  int wave = threadIdx.x >> 6, lane = threadIdx.x & 63;
  long row = (long)blockIdx.x*4 + wave;            // b*H + h
  const f16_t* xr = x + row*16384 + lane;
  float ar[12], ai[12];
  #pragma unroll
  for (int k = 0; k < 12; k++){ ar[k] = 0.f; ai[k] = 0.f; }
  for (int w = 0; w < 256; w++){
    float xv = (float)xr[(long)w*64];
    const float4* t = &tw[w*6];
    #pragma unroll
    for (int k = 0; k < 6; k++){
      float4 tv = t[k];
      ar[2*k]   += xv*tv.x;  ai[2*k]   += xv*tv.y;
      ar[2*k+1] += xv*tv.z;  ai[2*k+1] += xv*tv.w;
    }
  }
  float2* op = fft1 + row*768 + lane;
  #pragma unroll
  for (int ky = 0; ky < 12; ky++) op[ky*64] = make_float2(ar[ky], ai[ky]);
}

// ---- FUSED spectral chain: dft_h + mode-mix + ifft_h, block=(b,ky) ---------
__global__ __launch_bounds__(256) void k_spec(const float2* __restrict__ s0,
      const float2* __restrict__ s1, int dual, const float2* __restrict__ thf_g,
      const float2* __restrict__ thi_g, const float2* __restrict__ wmix,
      int layer, float2* __restrict__ zi){
  __shared__ __align__(16) char sm[40960];
  float2* th  = (float2*)sm;            // 3072 f2: thf (A) then thi (C)
  float2* xch = (float2*)(sm + 24576);  // 2048 f2 staging (A)
  float2* mixL= (float2*)(sm + 24576);  // [24 j][64 o] (B->C), aliases xch
  int tid = threadIdx.x;
  int b = blockIdx.x / 12, ky = blockIdx.x % 12;
  int wv = tid >> 6, lane = tid & 63;
  for (int f = tid; f < 3072; f += 256) th[f] = thf_g[f];
  // Stage A: h-DFT. acc[q] = xft[j=q*4+wv][c=lane]
  float2 acc[6];
  #pragma unroll
  for (int q = 0; q < 6; q++) acc[q] = make_float2(0.f, 0.f);
  long base = (long)b*98304 + ky*64;
  for (int ch = 0; ch < 4; ch++){
    __syncthreads();
    for (int f = tid; f < 2048; f += 256){
      int hh = f >> 6, c = f & 63;
      long idx = base + (long)(ch*32 + hh)*768 + c;
      float2 v = s0[idx];
      if (dual){ float2 u = s1[idx]; v.x += u.x; v.y += u.y; }
      xch[f] = v;
    }
    __syncthreads();
    for (int hh = 0; hh < 32; hh++){
      float2 v = xch[hh*64 + lane];
      int hg = ch*32 + hh;
      #pragma unroll
      for (int q = 0; q < 6; q++){
        float2 t = th[hg*24 + q*4 + wv];
        acc[q].x += t.x*v.x - t.y*v.y;
        acc[q].y += t.x*v.y + t.y*v.x;
      }
    }
  }
  __syncthreads();                      // A done: xch & thf dead after here
  for (int f = tid; f < 3072; f += 256) th[f] = thi_g[f];   // stage thi
  // Stage B: mode-mix, register-resident via shfl
  float2 mout[6];
  #pragma unroll
  for (int q = 0; q < 6; q++){
    int j = q*4 + wv;
    const float2* wj = wmix + (((long)layer*288 + j*12 + ky))*4096;
    float re = 0.f, im = 0.f;
    #pragma unroll 8
    for (int i = 0; i < 64; i++){
      float vr = __shfl(acc[q].x, i);
      float vi = __shfl(acc[q].y, i);
      float2 ww = wj[i*64 + lane];
      re += vr*ww.x - vi*ww.y;
      im += vr*ww.y + vi*ww.x;
    }
    mout[q] = make_float2(re, im);
  }
  #pragma unroll
  for (int q = 0; q < 6; q++) mixL[(q*4 + wv)*64 + lane] = mout[q];
  __syncthreads();                      // mixL + thi ready
  // Stage C: inverse h-DFT
  float2 cr[24];
  #pragma unroll
  for (int j = 0; j < 24; j++) cr[j] = mixL[j*64 + lane];
  for (int qq = 0; qq < 32; qq++){
    int h = qq*4 + wv;
    float re = 0.f, im = 0.f;
    #pragma unroll
    for (int j = 0; j < 24; j++){
      float2 t = th[h*24 + j];
      re += t.x*cr[j].x - t.y*cr[j].y;
      im += t.x*cr[j].y + t.y*cr[j].x;
    }
    zi[((long)b*128 + h)*768 + ky*64 + lane] = make_float2(re, im);
  }
}

// ------- MFMA: inverse-w + skip + bias + (gelu), in place on x,
//         fused next-layer partial w-DFT via MFMA (twA hi/lo) ----------------
__global__ __launch_bounds__(256) void k_iw_mfma(f16_t* __restrict__ x,
      const float2* __restrict__ zi, const float* __restrict__ ws_w,
      const float* __restrict__ ws_b, const f16_t* __restrict__ twzh,
      const f16_t* __restrict__ twA, float2* __restrict__ fp0,
      float2* __restrict__ fp1, int layer, int act, int dodft){
  __shared__ __align__(16) char sm[52736];
  f16_t* A  = (f16_t*)sm;                   // [128][136] phase1
  f16_t* Bm = (f16_t*)(sm + 34816);         // [64][136]  phase1
  float* sb = (float*)(sm + 52224);         // [64]
  f16_t* Obt  = (f16_t*)sm;                 // [64 c][136 w-pad] phase2 (dodft)
  f16_t* twA_l= (f16_t*)(sm + 17408);       // [2 hl][32 m][136 k-pad]
  int tid = threadIdx.x;
  int blk = blockIdx.x;
  int half = blk & 1;
  long bh = blk >> 1;                       // b*128 + h
  int w0 = half*128;
  const f16_t* xrow = x + (bh*256 + w0)*64;
  for (int f = tid; f < 1024; f += 256){    // x part, 16B copies
    int px = f >> 3, c8 = (f & 7)*8;
    *(float4*)((char*)A + (px*136 + c8)*2) = *(const float4*)(xrow + px*64 + c8);
  }
  for (int f = tid; f < 4096; f += 256){    // twz + zero pad (pow2, no div)
    int px = f >> 5, k = f & 31;
    if (k < 24){
      f16_t v = twzh[(w0+px)*32 + k];
      A[px*136 + 64 + k] = v;
      A[px*136 + 88 + k] = v;
      A[px*136 + 112 + k] = (f16_t)0.f;
    }
  }
  const float* wsl = ws_w + (long)layer*4096;
  for (int f = tid; f < 1024; f += 256){    // B ws part
    int o = f >> 4, c4 = f & 15;
    float4 v = *(const float4*)(wsl + o*64 + c4*4);
    f16_t* d = Bm + o*136 + c4*4;
    d[0]=(f16_t)v.x; d[1]=(f16_t)v.y; d[2]=(f16_t)v.z; d[3]=(f16_t)v.w;
  }
  const float2* zrow = zi + bh*768;
  for (int f = tid; f < 768; f += 256){     // B z hi/lo
    int o = f & 63, ky = f >> 6;
    float2 v = zrow[ky*64 + o];
    f16_t hr = (f16_t)v.x; f16_t hi_ = (f16_t)v.y;
    Bm[o*136 + 64 + ky] = hr;
    Bm[o*136 + 76 + ky] = hi_;
    Bm[o*136 + 88 + ky] = (f16_t)(v.x - (float)hr);
    Bm[o*136 +100 + ky] = (f16_t)(v.y - (float)hi_);
  }
  for (int f = tid; f < 2048; f += 256){    // B zero pad (pow2, no div)
    int o = f >> 5, k = f & 31;
    if (k < 24) Bm[o*136 + 112 + k] = (f16_t)0.f;
  }
  if (tid < 64) sb[tid] = ws_b[layer*64 + tid];
  __syncthreads();
  int lane = tid & 63, wv = tid >> 6;
  int n15 = lane & 15, quad = lane >> 4;
  int n = wv*16 + n15;
  half8 bfr[4];
  #pragma unroll
  for (int kc = 0; kc < 4; kc++)
    bfr[kc] = *(const half8*)(Bm + n*136 + kc*32 + quad*8);
  floatx4 acc[8];
  #pragma unroll
  for (int mt = 0; mt < 8; mt++){
    floatx4 c = {0.f,0.f,0.f,0.f};
    #pragma unroll
    for (int kc = 0; kc < 4; kc++){
      half8 a = *(const half8*)(A + (mt*16 + n15)*136 + kc*32 + quad*8);
      c = __builtin_amdgcn_mfma_f32_16x16x32_f16(a, bfr[kc], c, 0, 0, 0);
    }
    acc[mt] = c;
  }
  float bias = sb[n];
  __syncthreads();                           // A/Bm dead -> Obt, twA_l
  // Epilogue: gelu+store x DIRECTLY from registers (C-layout 2B stores);
  // Obt (for dft B-frags) written only when dodft.
  f16_t* xo = x + (bh*256 + w0)*64;
  #pragma unroll
  for (int mt = 0; mt < 8; mt++){
    half4 hv;
    #pragma unroll
    for (int r = 0; r < 4; r++){
      float v = acc[mt][r] + bias;
      if (act) v = gelu_f(v);
      hv[r] = (f16_t)v;
      xo[(mt*16 + quad*4 + r)*64 + n] = hv[r];
    }
    if (dodft) *(half4*)(Obt + n*136 + mt*16 + quad*4) = hv;
  }
  if (dodft){                                // stage twA (this half), re-strided
    const f16_t* tsrc = twA + half*8192;
    for (int f = tid; f < 1024; f += 256){
      int hl = f >> 9, m = (f >> 4) & 31, kc8 = f & 15;
      *(float4*)(twA_l + hl*4352 + m*136 + kc8*8) = *(const float4*)(tsrc + f*8);
    }
    __syncthreads();
    half8 bfr2[4];
    #pragma unroll
    for (int ks = 0; ks < 4; ks++)
      bfr2[ks] = *(const half8*)(Obt + n*136 + ks*32 + quad*8);
    floatx4 dacc[2];
    dacc[0] = (floatx4){0.f,0.f,0.f,0.f};
    dacc[1] = (floatx4){0.f,0.f,0.f,0.f};
    #pragma unroll
    for (int hl = 0; hl < 2; hl++){
      #pragma unroll
      for (int mt = 0; mt < 2; mt++){
        #pragma unroll
        for (int ks = 0; ks < 4; ks++){
          half8 a = *(const half8*)(twA_l + hl*4352 + (mt*16 + n15)*136
                                    + ks*32 + quad*8);
          dacc[mt] = __builtin_amdgcn_mfma_f32_16x16x32_f16(a, bfr2[ks],
                                                            dacc[mt], 0,0,0);
        }
      }
    }
    float2* dst = half ? fp1 : fp0;
    #pragma unroll
    for (int mt = 0; mt < 2; mt++){
      int m0 = mt*16 + quad*4;
      if (m0 < 24){
        int ky0 = m0 >> 1;
        dst[bh*768 + ky0*64 + n]     = make_float2(dacc[mt][0], dacc[mt][1]);
        dst[bh*768 + (ky0+1)*64 + n] = make_float2(dacc[mt][2], dacc[mt][3]);
      }
    }
  }
}

// ------- MFMA conv 3x3 (per-batch weights) + gelu + head, fused; 64-px tiles -
__global__ __launch_bounds__(256) void k_conv_head(const f16_t* __restrict__ x,
      const float* __restrict__ ext, const f16_t* __restrict__ wT,
      const float* __restrict__ tb, const f16_t* __restrict__ f1T,
      const float* __restrict__ f1_b, const f16_t* __restrict__ f2T,
      const float* __restrict__ f2_b, const f16_t* __restrict__ f3T,
      const float* __restrict__ f3_b, float* __restrict__ out){
  __shared__ __align__(16) char sm[37632];
  f16_t* hf   = (f16_t*)sm;                 // [64][72]
  f16_t* z1   = (f16_t*)(sm + 9216);        // [64][136]
  f16_t* z2   = (f16_t*)(sm + 26624);       // [64][72]
  float* tbs  = (float*)(sm + 35840);
  float* f1bs = (float*)(sm + 36096);
  float* f2bs = (float*)(sm + 36608);
  f16_t* f3s  = (f16_t*)(sm + 36864);
  float* f3bs = (float*)(sm + 37120);
  f16_t* xt   = (f16_t*)sm;                 // [3][66][72] (conv phase)

  int tid = threadIdx.x;
  int blk = blockIdx.x;
  int wc = blk & 3, h = (blk >> 2) & 127, b = blk >> 9;
  int w0 = wc*64;
  int t_idx = (int)ext[b*6+3] - 5;

  if (tid < 64) tbs[tid] = tb[t_idx*64 + tid];
  else if (tid < 192) f1bs[tid-64] = f1_b[tid-64];
  else f2bs[tid-192] = f2_b[tid-192];
  if (tid < 128) f3s[tid] = f3T[tid];
  if (tid < 2) f3bs[tid] = f3_b[tid];

  for (int f = tid; f < 3168; f += 256){    // xt: 3 rows x 66 px x 64 c
    int c4 = f & 15, r = f >> 4;
    int dy = r/66, pxl = r%66;
    int hh = h - 1 + dy, wg = w0 - 1 + pxl;
    ushort4 v = {0,0,0,0};
    if (hh >= 0 && hh < HH_ && wg >= 0 && wg < WW_)
      v = *(const ushort4*)(x + (((long)b*HH_ + hh)*WW_ + wg)*64 + c4*4);
    *(ushort4*)((unsigned short*)xt + (dy*66 + pxl)*72 + c4*4) = v;
  }
  __syncthreads();

  int lane = tid & 63, wv = tid >> 6;
  int n15 = lane & 15, quad = lane >> 4;

  floatx4 acc[4];
  #pragma unroll
  for (int mt = 0; mt < 4; mt++) acc[mt] = (floatx4){0.f,0.f,0.f,0.f};
  const f16_t* wTt = wT + (long)t_idx*36864;
  for (int tap = 0; tap < 9; tap++){
    int dy = tap/3, dx = tap%3;
    const f16_t* wrow = wTt + (tap*64 + wv*16 + n15)*64;
    #pragma unroll
    for (int kc = 0; kc < 2; kc++){
      half8 bfrag = *(const half8*)(wrow + kc*32 + quad*8);
      #pragma unroll
      for (int mt = 0; mt < 4; mt++){
        int p = mt*16 + n15 + dx;
        half8 a = *(const half8*)(xt + (dy*66 + p)*72 + kc*32 + quad*8);
        acc[mt] = __builtin_amdgcn_mfma_f32_16x16x32_f16(a, bfrag, acc[mt], 0,0,0);
      }
    }
  }
  __syncthreads();                           // xt dead
  {
    int n = wv*16 + n15;
    float bias = tbs[n];
    #pragma unroll
    for (int mt = 0; mt < 4; mt++){
      #pragma unroll
      for (int r = 0; r < 4; r++){
        int m = mt*16 + quad*4 + r;
        hf[m*72 + n] = (f16_t)gelu_f(acc[mt][r] + bias);
      }
    }
  }
  __syncthreads();
  // z1 = gelu(hf . f1^T + f1_b): M=64 N=128 K=64
  #pragma unroll
  for (int nt = 0; nt < 2; nt++){
    int n = wv*32 + nt*16 + n15;
    float bias = f1bs[n];
    half8 bf0 = *(const half8*)(f1T + n*64 + quad*8);
    half8 bf1 = *(const half8*)(f1T + n*64 + 32 + quad*8);
    #pragma unroll
    for (int mt = 0; mt < 4; mt++){
      floatx4 c = {0.f,0.f,0.f,0.f};
      half8 a0 = *(const half8*)(hf + (mt*16 + n15)*72 + quad*8);
      half8 a1 = *(const half8*)(hf + (mt*16 + n15)*72 + 32 + quad*8);
      c = __builtin_amdgcn_mfma_f32_16x16x32_f16(a0, bf0, c, 0,0,0);
      c = __builtin_amdgcn_mfma_f32_16x16x32_f16(a1, bf1, c, 0,0,0);
      #pragma unroll
      for (int r = 0; r < 4; r++){
        int m = mt*16 + quad*4 + r;
        z1[m*136 + n] = (f16_t)gelu_f(c[r] + bias);
      }
    }
  }
  __syncthreads();
  // z2 = gelu(z1 . f2^T + f2_b): M=64 N=64 K=128
  {
    int n = wv*16 + n15;
    float bias = f2bs[n];
    half8 bf[4];
    #pragma unroll
    for (int kc = 0; kc < 4; kc++)
      bf[kc] = *(const half8*)(f2T + n*128 + kc*32 + quad*8);
    #pragma unroll
    for (int mt = 0; mt < 4; mt++){
      floatx4 c = {0.f,0.f,0.f,0.f};
      #pragma unroll
      for (int kc = 0; kc < 4; kc++){
        half8 a = *(const half8*)(z1 + (mt*16 + n15)*136 + kc*32 + quad*8);
        c = __builtin_amdgcn_mfma_f32_16x16x32_f16(a, bf[kc], c, 0,0,0);
      }
      #pragma unroll
      for (int r = 0; r < 4; r++){
        int m = mt*16 + quad*4 + r;
        z2[m*72 + n] = (f16_t)gelu_f(c[r] + bias);
      }
    }
  }
  __syncthreads();
  // f3: out[px][0..1]
  if (tid < 128){
    int px = tid >> 1, oo = tid & 1;
    const f16_t* zr = z2 + px*72;
    const f16_t* fr = f3s + oo*64;
    float a = f3bs[oo];
    #pragma unroll
    for (int g = 0; g < 8; g++){
      half8 zv = *(const half8*)(zr + g*8);
      half8 wv2 = *(const half8*)(fr + g*8);
      #pragma unroll
      for (int q = 0; q < 8; q++) a += (float)zv[q]*(float)wv2[q];
    }
    out[(((long)b*HH_ + h)*WW_ + w0 + px)*2 + oo] = a;
  }
}

extern "C" void kernel_launch(void* const* d_in, const int* in_sizes, int n_in,
                              void* d_out, int out_size, void* d_ws, size_t ws_size,
                              hipStream_t stream){
  const float* inp     = (const float*)d_in[0];
  const float* ext     = (const float*)d_in[1];
  const float* enc_w   = (const float*)d_in[2];
  const float* enc_b   = (const float*)d_in[3];
  const float* w1r     = (const float*)d_in[4];
  const float* w1i     = (const float*)d_in[5];
  const float* w2r     = (const float*)d_in[6];
  const float* w2i     = (const float*)d_in[7];
  const float* ws_w    = (const float*)d_in[8];
  const float* ws_b    = (const float*)d_in[9];
  const float* day_emb = (const float*)d_in[10];
  const float* hour_emb= (const float*)d_in[11];
  const float* e1_w    = (const float*)d_in[12];
  const float* e1_b    = (const float*)d_in[13];
  const float* e2_w    = (const float*)d_in[14];
  const float* e2_b    = (const float*)d_in[15];
  const float* tw      = (const float*)d_in[16];
  const float* tb      = (const float*)d_in[17];
  const float* f1_w    = (const float*)d_in[18];
  const float* f1_b    = (const float*)d_in[19];
  const float* f2_w    = (const float*)d_in[20];
  const float* f2_b    = (const float*)d_in[21];
  const float* f3_w    = (const float*)d_in[22];
  const float* f3_b    = (const float*)d_in[23];
  float* outp = (float*)d_out;

  const size_t need = 248652032;
  if (ws_size < need){
    k_diag<<<dim3(1), dim3(64), 0, stream>>>(outp, (float)(ws_size >> 20));
    return;
  }
  char* p = (char*)d_ws;
  f16_t*  x    = (f16_t*)(p);                    // 134217728 B
  float2* fp0  = (float2*)(p + 134217728);       // 25165824 B
  float2* fp1  = (float2*)(p + 159383552);       // 25165824 B
  float2* zi   = (float2*)(p + 184549376);       // 25165824 B
  float2* twf  = (float2*)(p + 209715200);       // 24576 B
  float2* thf  = (float2*)(p + 209739776);       // 24576 B
  float2* thi  = (float2*)(p + 209764352);       // 24576 B
  f16_t*  twzh = (f16_t*)(p + 209788928);        // 16384 B
  f16_t*  wT   = (f16_t*)(p + 209805312);        // 1032192 B
  f16_t*  f1T  = (f16_t*)(p + 210837504);        // 16384 B
  f16_t*  f2T  = (f16_t*)(p + 210853888);        // 16384 B
  f16_t*  f3T  = (f16_t*)(p + 210870272);        // 256 B
  float2* wmix = (float2*)(p + 210870528);       // 37748736 B
  f16_t*  twA  = (f16_t*)(p + 248619264);        // 32768 B

  k_prep<<<dim3(1001), dim3(256), 0, stream>>>(twf, thf, thi, twzh,
      f1_w, f2_w, f3_w, f1T, f2T, f3T, tw, wT, w1r, w1i, w2r, w2i, wmix, twA);
  k_gx<<<dim3(128, 32), dim3(256), 0, stream>>>(ext, day_emb, hour_emb,
      e1_w, e1_b, e2_w, e2_b, inp, enc_w, enc_b, x);
  k_dft_w<<<dim3(1024), dim3(256), 0, stream>>>(x, (const float4*)twf, fp0);
  for (int l = 0; l < 4; l++){
    k_spec<<<dim3(384), dim3(256), 0, stream>>>(fp0, fp1, (l > 0) ? 1 : 0,
                                                thf, thi, wmix, l, zi);
    k_iw_mfma<<<dim3(8192), dim3(256), 0, stream>>>(x, zi, ws_w, ws_b, twzh,
                       twA, fp0, fp1, l, (l < 3) ? 1 : 0, (l < 3) ? 1 : 0);
  }
  k_conv_head<<<dim3(16384), dim3(256), 0, stream>>>(x, ext, wT, tb,
                     f1T, f1_b, f2T, f2_b, f3T, f3_b, outp);
}

// Round 13
// 1392.609 us; speedup vs baseline: 1.1631x; 1.0083x over previous
//
#include <hip/hip_runtime.h>
#include <math.h>

#define BB 32
#define HH_ 128
#define WW_ 256

typedef _Float16 f16_t;
typedef _Float16 half8 __attribute__((ext_vector_type(8)));
typedef _Float16 half4 __attribute__((ext_vector_type(4)));
typedef float floatx4 __attribute__((ext_vector_type(4)));

__device__ __forceinline__ float gelu_f(float v){
  return 0.5f * v * (1.0f + erff(v * 0.70710678118654752f));
}

__global__ void k_diag(float* out, float v){ out[threadIdx.x] = v; }

// ---- merged prep: [0,113) tables+head-f16; [113,169) wprep;
//      [169,937) mixprep; [937,1001) twA (forward-dft MFMA A-matrix, hi/lo) --
__global__ __launch_bounds__(256) void k_prep(
      float2* twf, float2* thf, float2* thi, f16_t* twzh,
      const float* __restrict__ f1_w, const float* __restrict__ f2_w,
      const float* __restrict__ f3_w, f16_t* f1T, f16_t* f2T, f16_t* f3T,
      const float* __restrict__ tw, f16_t* __restrict__ wT,
      const float* __restrict__ w1r, const float* __restrict__ w1i,
      const float* __restrict__ w2r, const float* __restrict__ w2i,
      float2* __restrict__ wmix, f16_t* __restrict__ twA){
  __shared__ __align__(16) char smp[53248];
  const double PI2 = 6.283185307179586476925286766559;
  int blk = blockIdx.x, tid = threadIdx.x;
  if (blk < 113){
    int t = blk*256 + tid;
    if (t < 3072){                       // forward w-DFT: [w][ky]
      int w = t/12, ky = t%12;
      double a = -PI2 * (double)(w*ky) / 256.0;
      twf[t] = make_float2((float)cos(a), (float)sin(a));
    } else if (t < 6144){                // forward h-DFT: [h][j]
      int f = t-3072; int h = f/24, j = f%24;
      int kx = (j<12)? j : j+104;
      double a = -PI2 * (double)(h*kx) / 128.0;
      thf[f] = make_float2((float)cos(a), (float)sin(a));
    } else if (t < 9216){                // inverse h (includes 1/128)
      int f = t-6144; int h = f/24, j = f%24;
      int kx = (j<12)? j : j+104;
      double a = PI2 * (double)(h*kx) / 128.0;
      thi[f] = make_float2((float)(cos(a)/128.0), (float)(sin(a)/128.0));
    } else if (t < 12288){               // inverse w (c2r) coefs, f16
      int f = t-9216; int w = f/12, ky = f%12;
      double a = PI2 * (double)(w*ky) / 256.0;
      double s = (ky==0)? 1.0 : 2.0;
      twzh[w*32 + ky]      = (f16_t)( s*cos(a)/256.0);
      twzh[w*32 + 12 + ky] = (f16_t)(-s*sin(a)/256.0);
      if (ky < 8) twzh[w*32 + 24 + ky] = (f16_t)0.f;
    } else {
      int t2 = t - 12288;                // head weights -> f16
      if (t2 < 8192) f1T[t2] = (f16_t)f1_w[t2];
      else if (t2 < 16384) f2T[t2-8192] = (f16_t)f2_w[t2-8192];
      else if (t2 < 16512) f3T[t2-16384] = (f16_t)f3_w[t2-16384];
    }
  } else if (blk < 169){                 // conv weight transpose via LDS
    float* s = (float*)smp;              // [o16][c][tap]
    int b2 = blk - 113;
    int og = b2 & 3, tt = b2 >> 2;
    const float* src = tw + (long)tt*36864 + og*9216;
    for (int f = tid; f < 9216; f += 256) s[f] = src[f];
    __syncthreads();
    for (int f = tid; f < 9216; f += 256){
      int c = f & 63; int r = f >> 6;
      int o16 = r % 16, tap = r / 16;
      float v = s[(o16*64 + c)*9 + tap];
      wT[(((long)tt*9 + tap)*64 + og*16 + o16)*64 + c] = (f16_t)v;
    }
  } else if (blk < 937){                 // spectral weight transpose via LDS
    float* sr = (float*)smp;             // 6656 f
    float* si = (float*)(smp + 26624);   // 6656 f
    int b2 = blk - 169;                  // < 768
    int ig  = b2 & 7;
    int kx  = (b2 >> 3) % 12;
    int sel = (b2 / 96) & 1;
    int l   = b2 / 192;
    const float* wr = sel ? w2r : w1r;
    const float* wi = sel ? w2i : w1i;
    for (int f = tid; f < 6144; f += 256){
      int i8 = f / 768; int rem = f % 768;
      int o = rem / 12, ky = rem % 12;
      long addr = (((long)l*64 + ig*8 + i8)*64 + o)*144 + kx*12 + ky;
      sr[(i8*64 + o)*13 + ky] = wr[addr];
      si[(i8*64 + o)*13 + ky] = wi[addr];
    }
    __syncthreads();
    int j = sel ? (kx + 12) : kx;
    for (int f = tid; f < 6144; f += 256){
      int o = f & 63; int r = f >> 6;
      int ky = r % 12, i8 = r / 12;
      int sidx = (i8*64 + o)*13 + ky;
      wmix[(((long)l*288 + j*12 + ky))*4096 + (ig*8 + i8)*64 + o] =
          make_float2(sr[sidx], si[sidx]);
    }
  } else {                               // twA[half][hl][32 m][128 k] f16
    int t = (blk - 937)*256 + tid;       // < 16384
    int halfi = t >> 13, r = t & 8191;
    int hl = r >> 12, r2 = r & 4095;
    int m = r2 >> 7, k = r2 & 127;
    f16_t v = (f16_t)0.f;
    if (m < 24){
      int ky = m >> 1, ri = m & 1;
      int w = halfi*128 + k;
      double a = -PI2 * (double)(w*ky) / 256.0;
      float t32 = (float)(ri ? sin(a) : cos(a));
      f16_t hi = (f16_t)t32;
      v = hl ? (f16_t)(t32 - (float)hi) : hi;
    }
    twA[t] = v;
  }
}

// ---- ext MLP + gate + encoder fused: writes x[b,h,w,c] f16 directly --------
__global__ __launch_bounds__(256) void k_gx(const float* __restrict__ ext,
      const float* __restrict__ day_emb, const float* __restrict__ hour_emb,
      const float* __restrict__ e1_w, const float* __restrict__ e1_b,
      const float* __restrict__ e2_w, const float* __restrict__ e2_b,
      const float* __restrict__ inp, const float* __restrict__ enc_w,
      const float* __restrict__ enc_b, f16_t* __restrict__ x){
  int b = blockIdx.y;
  int hw = blockIdx.x*256 + threadIdx.x;
  __shared__ float s[64];
  __shared__ float ew[320];
  __shared__ float eb[64];
  if (threadIdx.x < 64){
    int j = threadIdx.x;
    const float* e = ext + b*6;
    float emb[6];
    emb[0] = e[0];
    int d  = (int)e[2];
    emb[1] = day_emb[d*2];  emb[2] = day_emb[d*2+1];
    int hr = (int)e[3];
    emb[3] = hour_emb[hr*3]; emb[4] = hour_emb[hr*3+1]; emb[5] = hour_emb[hr*3+2];
    float acc = e1_b[j];
    #pragma unroll
    for (int k = 0; k < 6; k++) acc += emb[k]*e1_w[j*6+k];
    s[j] = gelu_f(acc);
    eb[j] = enc_b[j];
  }
  for (int f = threadIdx.x; f < 320; f += 256) ew[f] = enc_w[f];
  __syncthreads();
  const float4* wrow = (const float4*)(e2_w + (long)hw*64);
  float acc = e2_b[hw];
  #pragma unroll
  for (int k = 0; k < 16; k++){
    float4 v = wrow[k];
    acc += v.x*s[4*k] + v.y*s[4*k+1] + v.z*s[4*k+2] + v.w*s[4*k+3];
  }
  float gv = gelu_f(acc);
  long pix = (long)b*(HH_*WW_) + hw;
  float4 ip = *(const float4*)(inp + pix*4);
  f16_t* xp = x + pix*64;
  #pragma unroll
  for (int c8 = 0; c8 < 8; c8++){
    half8 hv;
    #pragma unroll
    for (int e = 0; e < 8; e++){
      int c = c8*8 + e;
      const float* wr2 = ew + c*5;
      hv[e] = (f16_t)(eb[c] + ip.x*wr2[0] + ip.y*wr2[1] + ip.z*wr2[2]
                      + ip.w*wr2[3] + gv*wr2[4]);
    }
    *(half8*)(xp + c8*8) = hv;
  }
}

// ---------------- forward DFT along w (layer 0 only): fp0 -------------------
__global__ __launch_bounds__(256) void k_dft_w(const f16_t* __restrict__ x,
      const float4* __restrict__ twf4, float2* __restrict__ fft1){
  __shared__ float4 tw[1536];                      // [w][6]
  for (int f = threadIdx.x; f < 1536; f += 256) tw[f] = twf4[f];
  __syncthreads();
  int wave = threadIdx.x >> 6, lane = threadIdx.x & 63;
  long row = (long)blockIdx.x*4 + wave;            // b*H + h
  const f16_t* xr = x + row*16384 + lane;
  float ar[12], ai[12];
  #pragma unroll
  for (int k = 0; k < 12; k++){ ar[k] = 0.f; ai[k] = 0.f; }
  for (int w = 0; w < 256; w++){
    float xv = (float)xr[(long)w*64];
    const float4* t = &tw[w*6];
    #pragma unroll
    for (int k = 0; k < 6; k++){
      float4 tv = t[k];
      ar[2*k]   += xv*tv.x;  ai[2*k]   += xv*tv.y;
      ar[2*k+1] += xv*tv.z;  ai[2*k+1] += xv*tv.w;
    }
  }
  float2* op = fft1 + row*768 + lane;
  #pragma unroll
  for (int ky = 0; ky < 12; ky++) op[ky*64] = make_float2(ar[ky], ai[ky]);
}

// ---- FUSED spectral chain: dft_h + mode-mix + ifft_h, block=(b,ky),
//      512 threads (8 waves: 3 modes/wave, 16 h/wave) for latency hiding ----
__global__ __launch_bounds__(512) void k_spec(const float2* __restrict__ s0,
      const float2* __restrict__ s1, int dual, const float2* __restrict__ thf_g,
      const float2* __restrict__ thi_g, const float2* __restrict__ wmix,
      int layer, float2* __restrict__ zi){
  __shared__ __align__(16) char sm[40960];
  float2* th  = (float2*)sm;            // 3072 f2: thf (A) then thi (C)
  float2* xch = (float2*)(sm + 24576);  // 2048 f2 staging (A)
  float2* mixL= (float2*)(sm + 24576);  // [24 j][64 o] (B->C), aliases xch
  int tid = threadIdx.x;
  int b = blockIdx.x / 12, ky = blockIdx.x % 12;
  int wv = tid >> 6, lane = tid & 63;   // wv in 0..7
  for (int f = tid; f < 3072; f += 512) th[f] = thf_g[f];
  // Stage A: h-DFT. acc[q] = xft[j=q*8+wv][c=lane]
  float2 acc[3];
  #pragma unroll
  for (int q = 0; q < 3; q++) acc[q] = make_float2(0.f, 0.f);
  long base = (long)b*98304 + ky*64;
  for (int ch = 0; ch < 4; ch++){
    __syncthreads();
    for (int f = tid; f < 2048; f += 512){
      int hh = f >> 6, c = f & 63;
      long idx = base + (long)(ch*32 + hh)*768 + c;
      float2 v = s0[idx];
      if (dual){ float2 u = s1[idx]; v.x += u.x; v.y += u.y; }
      xch[f] = v;
    }
    __syncthreads();
    for (int hh = 0; hh < 32; hh++){
      float2 v = xch[hh*64 + lane];
      int hg = ch*32 + hh;
      #pragma unroll
      for (int q = 0; q < 3; q++){
        float2 t = th[hg*24 + q*8 + wv];
        acc[q].x += t.x*v.x - t.y*v.y;
        acc[q].y += t.x*v.y + t.y*v.x;
      }
    }
  }
  __syncthreads();                      // A done: xch & thf dead after here
  for (int f = tid; f < 3072; f += 512) th[f] = thi_g[f];   // stage thi
  // Stage B: mode-mix, register-resident via shfl
  float2 mout[3];
  #pragma unroll
  for (int q = 0; q < 3; q++){
    int j = q*8 + wv;
    const float2* wj = wmix + (((long)layer*288 + j*12 + ky))*4096;
    float re = 0.f, im = 0.f;
    #pragma unroll 8
    for (int i = 0; i < 64; i++){
      float vr = __shfl(acc[q].x, i);
      float vi = __shfl(acc[q].y, i);
      float2 ww = wj[i*64 + lane];
      re += vr*ww.x - vi*ww.y;
      im += vr*ww.y + vi*ww.x;
    }
    mout[q] = make_float2(re, im);
  }
  #pragma unroll
  for (int q = 0; q < 3; q++) mixL[(q*8 + wv)*64 + lane] = mout[q];
  __syncthreads();                      // mixL + thi ready
  // Stage C: inverse h-DFT
  float2 cr[24];
  #pragma unroll
  for (int j = 0; j < 24; j++) cr[j] = mixL[j*64 + lane];
  for (int qq = 0; qq < 16; qq++){
    int h = qq*8 + wv;
    float re = 0.f, im = 0.f;
    #pragma unroll
    for (int j = 0; j < 24; j++){
      float2 t = th[h*24 + j];
      re += t.x*cr[j].x - t.y*cr[j].y;
      im += t.x*cr[j].y + t.y*cr[j].x;
    }
    zi[((long)b*128 + h)*768 + ky*64 + lane] = make_float2(re, im);
  }
}

// ------- MFMA: inverse-w + skip + bias + (gelu), in place on x,
//         fused next-layer partial w-DFT via MFMA (twA hi/lo) ----------------
__global__ __launch_bounds__(256) void k_iw_mfma(f16_t* __restrict__ x,
      const float2* __restrict__ zi, const float* __restrict__ ws_w,
      const float* __restrict__ ws_b, const f16_t* __restrict__ twzh,
      const f16_t* __restrict__ twA, float2* __restrict__ fp0,
      float2* __restrict__ fp1, int layer, int act, int dodft){
  __shared__ __align__(16) char sm[52736];
  f16_t* A  = (f16_t*)sm;                   // [128][136] phase1
  f16_t* Bm = (f16_t*)(sm + 34816);         // [64][136]  phase1
  float* sb = (float*)(sm + 52224);         // [64]
  f16_t* Obt  = (f16_t*)sm;                 // [64 c][136 w-pad] phase2 (dodft)
  f16_t* twA_l= (f16_t*)(sm + 17408);       // [2 hl][32 m][136 k-pad]
  int tid = threadIdx.x;
  int blk = blockIdx.x;
  int half = blk & 1;
  long bh = blk >> 1;                       // b*128 + h
  int w0 = half*128;
  const f16_t* xrow = x + (bh*256 + w0)*64;
  for (int f = tid; f < 1024; f += 256){    // x part, 16B copies
    int px = f >> 3, c8 = (f & 7)*8;
    *(float4*)((char*)A + (px*136 + c8)*2) = *(const float4*)(xrow + px*64 + c8);
  }
  for (int f = tid; f < 4096; f += 256){    // twz + zero pad (pow2, no div)
    int px = f >> 5, k = f & 31;
    if (k < 24){
      f16_t v = twzh[(w0+px)*32 + k];
      A[px*136 + 64 + k] = v;
      A[px*136 + 88 + k] = v;
      A[px*136 + 112 + k] = (f16_t)0.f;
    }
  }
  const float* wsl = ws_w + (long)layer*4096;
  for (int f = tid; f < 1024; f += 256){    // B ws part
    int o = f >> 4, c4 = f & 15;
    float4 v = *(const float4*)(wsl + o*64 + c4*4);
    f16_t* d = Bm + o*136 + c4*4;
    d[0]=(f16_t)v.x; d[1]=(f16_t)v.y; d[2]=(f16_t)v.z; d[3]=(f16_t)v.w;
  }
  const float2* zrow = zi + bh*768;
  for (int f = tid; f < 768; f += 256){     // B z hi/lo
    int o = f & 63, ky = f >> 6;
    float2 v = zrow[ky*64 + o];
    f16_t hr = (f16_t)v.x; f16_t hi_ = (f16_t)v.y;
    Bm[o*136 + 64 + ky] = hr;
    Bm[o*136 + 76 + ky] = hi_;
    Bm[o*136 + 88 + ky] = (f16_t)(v.x - (float)hr);
    Bm[o*136 +100 + ky] = (f16_t)(v.y - (float)hi_);
  }
  for (int f = tid; f < 2048; f += 256){    // B zero pad (pow2, no div)
    int o = f >> 5, k = f & 31;
    if (k < 24) Bm[o*136 + 112 + k] = (f16_t)0.f;
  }
  if (tid < 64) sb[tid] = ws_b[layer*64 + tid];
  __syncthreads();
  int lane = tid & 63, wv = tid >> 6;
  int n15 = lane & 15, quad = lane >> 4;
  int n = wv*16 + n15;
  half8 bfr[4];
  #pragma unroll
  for (int kc = 0; kc < 4; kc++)
    bfr[kc] = *(const half8*)(Bm + n*136 + kc*32 + quad*8);
  floatx4 acc[8];
  #pragma unroll
  for (int mt = 0; mt < 8; mt++){
    floatx4 c = {0.f,0.f,0.f,0.f};
    #pragma unroll
    for (int kc = 0; kc < 4; kc++){
      half8 a = *(const half8*)(A + (mt*16 + n15)*136 + kc*32 + quad*8);
      c = __builtin_amdgcn_mfma_f32_16x16x32_f16(a, bfr[kc], c, 0, 0, 0);
    }
    acc[mt] = c;
  }
  float bias = sb[n];
  __syncthreads();                           // A/Bm dead -> Obt, twA_l
  f16_t* xo = x + (bh*256 + w0)*64;
  #pragma unroll
  for (int mt = 0; mt < 8; mt++){
    half4 hv;
    #pragma unroll
    for (int r = 0; r < 4; r++){
      float v = acc[mt][r] + bias;
      if (act) v = gelu_f(v);
      hv[r] = (f16_t)v;
      xo[(mt*16 + quad*4 + r)*64 + n] = hv[r];
    }
    if (dodft) *(half4*)(Obt + n*136 + mt*16 + quad*4) = hv;
  }
  if (dodft){                                // stage twA (this half), re-strided
    const f16_t* tsrc = twA + half*8192;
    for (int f = tid; f < 1024; f += 256){
      int hl = f >> 9, m = (f >> 4) & 31, kc8 = f & 15;
      *(float4*)(twA_l + hl*4352 + m*136 + kc8*8) = *(const float4*)(tsrc + f*8);
    }
    __syncthreads();
    half8 bfr2[4];
    #pragma unroll
    for (int ks = 0; ks < 4; ks++)
      bfr2[ks] = *(const half8*)(Obt + n*136 + ks*32 + quad*8);
    floatx4 dacc[2];
    dacc[0] = (floatx4){0.f,0.f,0.f,0.f};
    dacc[1] = (floatx4){0.f,0.f,0.f,0.f};
    #pragma unroll
    for (int hl = 0; hl < 2; hl++){
      #pragma unroll
      for (int mt = 0; mt < 2; mt++){
        #pragma unroll
        for (int ks = 0; ks < 4; ks++){
          half8 a = *(const half8*)(twA_l + hl*4352 + (mt*16 + n15)*136
                                    + ks*32 + quad*8);
          dacc[mt] = __builtin_amdgcn_mfma_f32_16x16x32_f16(a, bfr2[ks],
                                                            dacc[mt], 0,0,0);
        }
      }
    }
    float2* dst = half ? fp1 : fp0;
    #pragma unroll
    for (int mt = 0; mt < 2; mt++){
      int m0 = mt*16 + quad*4;
      if (m0 < 24){
        int ky0 = m0 >> 1;
        dst[bh*768 + ky0*64 + n]     = make_float2(dacc[mt][0], dacc[mt][1]);
        dst[bh*768 + (ky0+1)*64 + n] = make_float2(dacc[mt][2], dacc[mt][3]);
      }
    }
  }
}

// ------- MFMA conv 3x3 (per-batch weights) + gelu + head, fused; 64-px tiles -
__global__ __launch_bounds__(256) void k_conv_head(const f16_t* __restrict__ x,
      const float* __restrict__ ext, const f16_t* __restrict__ wT,
      const float* __restrict__ tb, const f16_t* __restrict__ f1T,
      const float* __restrict__ f1_b, const f16_t* __restrict__ f2T,
      const float* __restrict__ f2_b, const f16_t* __restrict__ f3T,
      const float* __restrict__ f3_b, float* __restrict__ out){
  __shared__ __align__(16) char sm[37632];
  f16_t* hf   = (f16_t*)sm;                 // [64][72]
  f16_t* z1   = (f16_t*)(sm + 9216);        // [64][136]
  f16_t* z2   = (f16_t*)(sm + 26624);       // [64][72]
  float* tbs  = (float*)(sm + 35840);
  float* f1bs = (float*)(sm + 36096);
  float* f2bs = (float*)(sm + 36608);
  f16_t* f3s  = (f16_t*)(sm + 36864);
  float* f3bs = (float*)(sm + 37120);
  f16_t* xt   = (f16_t*)sm;                 // [3][66][72] (conv phase)

  int tid = threadIdx.x;
  int blk = blockIdx.x;
  int wc = blk & 3, h = (blk >> 2) & 127, b = blk >> 9;
  int w0 = wc*64;
  int t_idx = (int)ext[b*6+3] - 5;

  if (tid < 64) tbs[tid] = tb[t_idx*64 + tid];
  else if (tid < 192) f1bs[tid-64] = f1_b[tid-64];
  else f2bs[tid-192] = f2_b[tid-192];
  if (tid < 128) f3s[tid] = f3T[tid];
  if (tid < 2) f3bs[tid] = f3_b[tid];

  for (int f = tid; f < 1584; f += 256){    // xt: 3 rows x 66 px x 8 chunks, 16B
    int c8 = f & 7, r = f >> 3;
    int dy = r/66, pxl = r%66;
    int hh = h - 1 + dy, wg = w0 - 1 + pxl;
    float4 v = {0.f,0.f,0.f,0.f};
    if (hh >= 0 && hh < HH_ && wg >= 0 && wg < WW_)
      v = *(const float4*)(x + (((long)b*HH_ + hh)*WW_ + wg)*64 + c8*8);
    *(float4*)(xt + (dy*66 + pxl)*72 + c8*8) = v;
  }
  __syncthreads();

  int lane = tid & 63, wv = tid >> 6;
  int n15 = lane & 15, quad = lane >> 4;

  floatx4 acc[4];
  #pragma unroll
  for (int mt = 0; mt < 4; mt++) acc[mt] = (floatx4){0.f,0.f,0.f,0.f};
  const f16_t* wTt = wT + (long)t_idx*36864;
  for (int tap = 0; tap < 9; tap++){
    int dy = tap/3, dx = tap%3;
    const f16_t* wrow = wTt + (tap*64 + wv*16 + n15)*64;
    #pragma unroll
    for (int kc = 0; kc < 2; kc++){
      half8 bfrag = *(const half8*)(wrow + kc*32 + quad*8);
      #pragma unroll
      for (int mt = 0; mt < 4; mt++){
        int p = mt*16 + n15 + dx;
        half8 a = *(const half8*)(xt + (dy*66 + p)*72 + kc*32 + quad*8);
        acc[mt] = __builtin_amdgcn_mfma_f32_16x16x32_f16(a, bfrag, acc[mt], 0,0,0);
      }
    }
  }
  __syncthreads();                           // xt dead
  {
    int n = wv*16 + n15;
    float bias = tbs[n];
    #pragma unroll
    for (int mt = 0; mt < 4; mt++){
      #pragma unroll
      for (int r = 0; r < 4; r++){
        int m = mt*16 + quad*4 + r;
        hf[m*72 + n] = (f16_t)gelu_f(acc[mt][r] + bias);
      }
    }
  }
  __syncthreads();
  // z1 = gelu(hf . f1^T + f1_b): M=64 N=128 K=64
  #pragma unroll
  for (int nt = 0; nt < 2; nt++){
    int n = wv*32 + nt*16 + n15;
    float bias = f1bs[n];
    half8 bf0 = *(const half8*)(f1T + n*64 + quad*8);
    half8 bf1 = *(const half8*)(f1T + n*64 + 32 + quad*8);
    #pragma unroll
    for (int mt = 0; mt < 4; mt++){
      floatx4 c = {0.f,0.f,0.f,0.f};
      half8 a0 = *(const half8*)(hf + (mt*16 + n15)*72 + quad*8);
      half8 a1 = *(const half8*)(hf + (mt*16 + n15)*72 + 32 + quad*8);
      c = __builtin_amdgcn_mfma_f32_16x16x32_f16(a0, bf0, c, 0,0,0);
      c = __builtin_amdgcn_mfma_f32_16x16x32_f16(a1, bf1, c, 0,0,0);
      #pragma unroll
      for (int r = 0; r < 4; r++){
        int m = mt*16 + quad*4 + r;
        z1[m*136 + n] = (f16_t)gelu_f(c[r] + bias);
      }
    }
  }
  __syncthreads();
  // z2 = gelu(z1 . f2^T + f2_b): M=64 N=64 K=128
  {
    int n = wv*16 + n15;
    float bias = f2bs[n];
    half8 bf[4];
    #pragma unroll
    for (int kc = 0; kc < 4; kc++)
      bf[kc] = *(const half8*)(f2T + n*128 + kc*32 + quad*8);
    #pragma unroll
    for (int mt = 0; mt < 4; mt++){
      floatx4 c = {0.f,0.f,0.f,0.f};
      #pragma unroll
      for (int kc = 0; kc < 4; kc++){
        half8 a = *(const half8*)(z1 + (mt*16 + n15)*136 + kc*32 + quad*8);
        c = __builtin_amdgcn_mfma_f32_16x16x32_f16(a, bf[kc], c, 0,0,0);
      }
      #pragma unroll
      for (int r = 0; r < 4; r++){
        int m = mt*16 + quad*4 + r;
        z2[m*72 + n] = (f16_t)gelu_f(c[r] + bias);
      }
    }
  }
  __syncthreads();
  // f3: out[px][0..1]
  if (tid < 128){
    int px = tid >> 1, oo = tid & 1;
    const f16_t* zr = z2 + px*72;
    const f16_t* fr = f3s + oo*64;
    float a = f3bs[oo];
    #pragma unroll
    for (int g = 0; g < 8; g++){
      half8 zv = *(const half8*)(zr + g*8);
      half8 wv2 = *(const half8*)(fr + g*8);
      #pragma unroll
      for (int q = 0; q < 8; q++) a += (float)zv[q]*(float)wv2[q];
    }
    out[(((long)b*HH_ + h)*WW_ + w0 + px)*2 + oo] = a;
  }
}

extern "C" void kernel_launch(void* const* d_in, const int* in_sizes, int n_in,
                              void* d_out, int out_size, void* d_ws, size_t ws_size,
                              hipStream_t stream){
  const float* inp     = (const float*)d_in[0];
  const float* ext     = (const float*)d_in[1];
  const float* enc_w   = (const float*)d_in[2];
  const float* enc_b   = (const float*)d_in[3];
  const float* w1r     = (const float*)d_in[4];
  const float* w1i     = (const float*)d_in[5];
  const float* w2r     = (const float*)d_in[6];
  const float* w2i     = (const float*)d_in[7];
  const float* ws_w    = (const float*)d_in[8];
  const float* ws_b    = (const float*)d_in[9];
  const float* day_emb = (const float*)d_in[10];
  const float* hour_emb= (const float*)d_in[11];
  const float* e1_w    = (const float*)d_in[12];
  const float* e1_b    = (const float*)d_in[13];
  const float* e2_w    = (const float*)d_in[14];
  const float* e2_b    = (const float*)d_in[15];
  const float* tw      = (const float*)d_in[16];
  const float* tb      = (const float*)d_in[17];
  const float* f1_w    = (const float*)d_in[18];
  const float* f1_b    = (const float*)d_in[19];
  const float* f2_w    = (const float*)d_in[20];
  const float* f2_b    = (const float*)d_in[21];
  const float* f3_w    = (const float*)d_in[22];
  const float* f3_b    = (const float*)d_in[23];
  float* outp = (float*)d_out;

  const size_t need = 248652032;
  if (ws_size < need){
    k_diag<<<dim3(1), dim3(64), 0, stream>>>(outp, (float)(ws_size >> 20));
    return;
  }
  char* p = (char*)d_ws;
  f16_t*  x    = (f16_t*)(p);                    // 134217728 B
  float2* fp0  = (float2*)(p + 134217728);       // 25165824 B
  float2* fp1  = (float2*)(p + 159383552);       // 25165824 B
  float2* zi   = (float2*)(p + 184549376);       // 25165824 B
  float2* twf  = (float2*)(p + 209715200);       // 24576 B
  float2* thf  = (float2*)(p + 209739776);       // 24576 B
  float2* thi  = (float2*)(p + 209764352);       // 24576 B
  f16_t*  twzh = (f16_t*)(p + 209788928);        // 16384 B
  f16_t*  wT   = (f16_t*)(p + 209805312);        // 1032192 B
  f16_t*  f1T  = (f16_t*)(p + 210837504);        // 16384 B
  f16_t*  f2T  = (f16_t*)(p + 210853888);        // 16384 B
  f16_t*  f3T  = (f16_t*)(p + 210870272);        // 256 B
  float2* wmix = (float2*)(p + 210870528);       // 37748736 B
  f16_t*  twA  = (f16_t*)(p + 248619264);        // 32768 B

  k_prep<<<dim3(1001), dim3(256), 0, stream>>>(twf, thf, thi, twzh,
      f1_w, f2_w, f3_w, f1T, f2T, f3T, tw, wT, w1r, w1i, w2r, w2i, wmix, twA);
  k_gx<<<dim3(128, 32), dim3(256), 0, stream>>>(ext, day_emb, hour_emb,
      e1_w, e1_b, e2_w, e2_b, inp, enc_w, enc_b, x);
  k_dft_w<<<dim3(1024), dim3(256), 0, stream>>>(x, (const float4*)twf, fp0);
  for (int l = 0; l < 4; l++){
    k_spec<<<dim3(384), dim3(512), 0, stream>>>(fp0, fp1, (l > 0) ? 1 : 0,
                                                thf, thi, wmix, l, zi);
    k_iw_mfma<<<dim3(8192), dim3(256), 0, stream>>>(x, zi, ws_w, ws_b, twzh,
                       twA, fp0, fp1, l, (l < 3) ? 1 : 0, (l < 3) ? 1 : 0);
  }
  k_conv_head<<<dim3(16384), dim3(256), 0, stream>>>(x, ext, wT, tb,
                     f1T, f1_b, f2T, f2_b, f3T, f3_b, outp);
}

// Round 14
// 1328.705 us; speedup vs baseline: 1.2190x; 1.0481x over previous
//
#include <hip/hip_runtime.h>
#include <math.h>

#define BB 32
#define HH_ 128
#define WW_ 256

typedef _Float16 f16_t;
typedef _Float16 half8 __attribute__((ext_vector_type(8)));
typedef _Float16 half4 __attribute__((ext_vector_type(4)));
typedef float floatx4 __attribute__((ext_vector_type(4)));

__device__ __forceinline__ float gelu_f(float v){
  return 0.5f * v * (1.0f + erff(v * 0.70710678118654752f));
}

__global__ void k_diag(float* out, float v){ out[threadIdx.x] = v; }

// ---- merged prep: [0,113) tables+head-f16; [113,169) wprep;
//      [169,937) mixprep; [937,1001) twA (forward-dft MFMA A-matrix, hi/lo) --
__global__ __launch_bounds__(256) void k_prep(
      float2* twf, float2* thf, float2* thi, f16_t* twzh,
      const float* __restrict__ f1_w, const float* __restrict__ f2_w,
      const float* __restrict__ f3_w, f16_t* f1T, f16_t* f2T, f16_t* f3T,
      const float* __restrict__ tw, f16_t* __restrict__ wT,
      const float* __restrict__ w1r, const float* __restrict__ w1i,
      const float* __restrict__ w2r, const float* __restrict__ w2i,
      float2* __restrict__ wmix, f16_t* __restrict__ twA){
  __shared__ __align__(16) char smp[53248];
  const double PI2 = 6.283185307179586476925286766559;
  int blk = blockIdx.x, tid = threadIdx.x;
  if (blk < 113){
    int t = blk*256 + tid;
    if (t < 3072){                       // forward w-DFT: [w][ky] (unused now)
      int w = t/12, ky = t%12;
      double a = -PI2 * (double)(w*ky) / 256.0;
      twf[t] = make_float2((float)cos(a), (float)sin(a));
    } else if (t < 6144){                // forward h-DFT: [h][j]
      int f = t-3072; int h = f/24, j = f%24;
      int kx = (j<12)? j : j+104;
      double a = -PI2 * (double)(h*kx) / 128.0;
      thf[f] = make_float2((float)cos(a), (float)sin(a));
    } else if (t < 9216){                // inverse h (includes 1/128)
      int f = t-6144; int h = f/24, j = f%24;
      int kx = (j<12)? j : j+104;
      double a = PI2 * (double)(h*kx) / 128.0;
      thi[f] = make_float2((float)(cos(a)/128.0), (float)(sin(a)/128.0));
    } else if (t < 12288){               // inverse w (c2r) coefs, f16
      int f = t-9216; int w = f/12, ky = f%12;
      double a = PI2 * (double)(w*ky) / 256.0;
      double s = (ky==0)? 1.0 : 2.0;
      twzh[w*32 + ky]      = (f16_t)( s*cos(a)/256.0);
      twzh[w*32 + 12 + ky] = (f16_t)(-s*sin(a)/256.0);
      if (ky < 8) twzh[w*32 + 24 + ky] = (f16_t)0.f;
    } else {
      int t2 = t - 12288;                // head weights -> f16
      if (t2 < 8192) f1T[t2] = (f16_t)f1_w[t2];
      else if (t2 < 16384) f2T[t2-8192] = (f16_t)f2_w[t2-8192];
      else if (t2 < 16512) f3T[t2-16384] = (f16_t)f3_w[t2-16384];
    }
  } else if (blk < 169){                 // conv weight transpose via LDS
    float* s = (float*)smp;              // [o16][c][tap]
    int b2 = blk - 113;
    int og = b2 & 3, tt = b2 >> 2;
    const float* src = tw + (long)tt*36864 + og*9216;
    for (int f = tid; f < 9216; f += 256) s[f] = src[f];
    __syncthreads();
    for (int f = tid; f < 9216; f += 256){
      int c = f & 63; int r = f >> 6;
      int o16 = r % 16, tap = r / 16;
      float v = s[(o16*64 + c)*9 + tap];
      wT[(((long)tt*9 + tap)*64 + og*16 + o16)*64 + c] = (f16_t)v;
    }
  } else if (blk < 937){                 // spectral weight transpose via LDS
    float* sr = (float*)smp;             // 6656 f
    float* si = (float*)(smp + 26624);   // 6656 f
    int b2 = blk - 169;                  // < 768
    int ig  = b2 & 7;
    int kx  = (b2 >> 3) % 12;
    int sel = (b2 / 96) & 1;
    int l   = b2 / 192;
    const float* wr = sel ? w2r : w1r;
    const float* wi = sel ? w2i : w1i;
    for (int f = tid; f < 6144; f += 256){
      int i8 = f / 768; int rem = f % 768;
      int o = rem / 12, ky = rem % 12;
      long addr = (((long)l*64 + ig*8 + i8)*64 + o)*144 + kx*12 + ky;
      sr[(i8*64 + o)*13 + ky] = wr[addr];
      si[(i8*64 + o)*13 + ky] = wi[addr];
    }
    __syncthreads();
    int j = sel ? (kx + 12) : kx;
    for (int f = tid; f < 6144; f += 256){
      int o = f & 63; int r = f >> 6;
      int ky = r % 12, i8 = r / 12;
      int sidx = (i8*64 + o)*13 + ky;
      wmix[(((long)l*288 + j*12 + ky))*4096 + (ig*8 + i8)*64 + o] =
          make_float2(sr[sidx], si[sidx]);
    }
  } else {                               // twA[half][hl][32 m][128 k] f16
    int t = (blk - 937)*256 + tid;       // < 16384
    int halfi = t >> 13, r = t & 8191;
    int hl = r >> 12, r2 = r & 4095;
    int m = r2 >> 7, k = r2 & 127;
    f16_t v = (f16_t)0.f;
    if (m < 24){
      int ky = m >> 1, ri = m & 1;
      int w = halfi*128 + k;
      double a = -PI2 * (double)(w*ky) / 256.0;
      float t32 = (float)(ri ? sin(a) : cos(a));
      f16_t hi = (f16_t)t32;
      v = hl ? (f16_t)(t32 - (float)hi) : hi;
    }
    twA[t] = v;
  }
}

// ---- ext MLP + gate + encoder + layer-0 w-DFT (MFMA), block=(b,h) row ------
__global__ __launch_bounds__(256) void k_gxdft(const float* __restrict__ ext,
      const float* __restrict__ day_emb, const float* __restrict__ hour_emb,
      const float* __restrict__ e1_w, const float* __restrict__ e1_b,
      const float* __restrict__ e2_w, const float* __restrict__ e2_b,
      const float* __restrict__ inp, const float* __restrict__ enc_w,
      const float* __restrict__ enc_b, const f16_t* __restrict__ twA,
      f16_t* __restrict__ x, float2* __restrict__ fp0, float2* __restrict__ fp1){
  __shared__ __align__(16) char sm[59392];
  f16_t* Obt   = (f16_t*)sm;              // [64 c][274 w-pad]  35072 B
  f16_t* twA_l = (f16_t*)(sm + 35072);    // [2 hl][32 m][136]  17408 B
  float* gvs   = (float*)(sm + 52480);    // 256
  float4* ips  = (float4*)(sm + 53504);   // 256 float4
  float* s     = (float*)(sm + 57600);    // 64
  float* ew    = (float*)(sm + 57856);    // 320
  float* eb    = (float*)(sm + 59136);    // 64
  int tid = threadIdx.x;
  int bh = blockIdx.x;                    // b*128 + h
  int b = bh >> 7, h = bh & 127;
  if (tid < 64){
    int j = tid;
    const float* e = ext + b*6;
    float emb[6];
    emb[0] = e[0];
    int d  = (int)e[2];
    emb[1] = day_emb[d*2];  emb[2] = day_emb[d*2+1];
    int hr = (int)e[3];
    emb[3] = hour_emb[hr*3]; emb[4] = hour_emb[hr*3+1]; emb[5] = hour_emb[hr*3+2];
    float acc = e1_b[j];
    #pragma unroll
    for (int k = 0; k < 6; k++) acc += emb[k]*e1_w[j*6+k];
    s[j] = gelu_f(acc);
    eb[j] = enc_b[j];
  }
  for (int f = tid; f < 320; f += 256) ew[f] = enc_w[f];
  __syncthreads();
  {                                        // gate per pixel
    int px = tid;
    long hw = (long)h*256 + px;
    const float4* wrow = (const float4*)(e2_w + hw*64);
    float acc = e2_b[hw];
    #pragma unroll
    for (int k = 0; k < 16; k++){
      float4 v = wrow[k];
      acc += v.x*s[4*k] + v.y*s[4*k+1] + v.z*s[4*k+2] + v.w*s[4*k+3];
    }
    gvs[px] = gelu_f(acc);
    ips[px] = *(const float4*)(inp + ((long)b*32768 + hw)*4);
  }
  __syncthreads();
  int lane = tid & 63, wv = tid >> 6;
  {                                        // encoder: thread = (c, 64-px group)
    int c = lane, wg = wv;
    const float* wr2 = ew + c*5;
    float w0 = wr2[0], w1 = wr2[1], w2 = wr2[2], w3 = wr2[3], w4 = wr2[4];
    float ebc = eb[c];
    f16_t* xo = x + ((long)bh*256 + wg*64)*64 + c;
    #pragma unroll 2
    for (int g8 = 0; g8 < 8; g8++){
      half8 hv;
      #pragma unroll
      for (int e2 = 0; e2 < 8; e2++){
        int i = g8*8 + e2;
        float4 ip = ips[wg*64 + i];
        float gv = gvs[wg*64 + i];
        float v = ebc + ip.x*w0 + ip.y*w1 + ip.z*w2 + ip.w*w3 + gv*w4;
        f16_t hval = (f16_t)v;
        hv[e2] = hval;
        xo[i*64] = hval;                   // coalesced across lanes (same i)
      }
      *(half8*)(Obt + c*274 + wg*64 + g8*8) = hv;
    }
  }
  for (int f = tid; f < 1024; f += 256){   // stage twA half0
    int hl = f >> 9, m = (f >> 4) & 31, kc8 = f & 15;
    *(float4*)(twA_l + hl*4352 + m*136 + kc8*8) = *(const float4*)(twA + f*8);
  }
  __syncthreads();
  int n15 = lane & 15, quad = lane >> 4;
  int n = wv*16 + n15;
  #pragma unroll
  for (int half = 0; half < 2; half++){
    if (half == 1){
      __syncthreads();
      for (int f = tid; f < 1024; f += 256){
        int hl = f >> 9, m = (f >> 4) & 31, kc8 = f & 15;
        *(float4*)(twA_l + hl*4352 + m*136 + kc8*8) =
            *(const float4*)(twA + 8192 + f*8);
      }
      __syncthreads();
    }
    half8 bfr2[4];
    #pragma unroll
    for (int ks = 0; ks < 4; ks++)
      bfr2[ks] = *(const half8*)(Obt + n*274 + half*128 + ks*32 + quad*8);
    floatx4 dacc[2];
    dacc[0] = (floatx4){0.f,0.f,0.f,0.f};
    dacc[1] = (floatx4){0.f,0.f,0.f,0.f};
    #pragma unroll
    for (int hl = 0; hl < 2; hl++){
      #pragma unroll
      for (int mt = 0; mt < 2; mt++){
        #pragma unroll
        for (int ks = 0; ks < 4; ks++){
          half8 a = *(const half8*)(twA_l + hl*4352 + (mt*16 + n15)*136
                                    + ks*32 + quad*8);
          dacc[mt] = __builtin_amdgcn_mfma_f32_16x16x32_f16(a, bfr2[ks],
                                                            dacc[mt], 0,0,0);
        }
      }
    }
    float2* dst = half ? fp1 : fp0;
    #pragma unroll
    for (int mt = 0; mt < 2; mt++){
      int m0 = mt*16 + quad*4;
      if (m0 < 24){
        int ky0 = m0 >> 1;
        dst[(long)bh*768 + ky0*64 + n]     = make_float2(dacc[mt][0], dacc[mt][1]);
        dst[(long)bh*768 + (ky0+1)*64 + n] = make_float2(dacc[mt][2], dacc[mt][3]);
      }
    }
  }
}

// ---- FUSED spectral chain: dft_h + mode-mix + ifft_h, block=(b,ky) ---------
__global__ __launch_bounds__(256) void k_spec(const float2* __restrict__ s0,
      const float2* __restrict__ s1, int dual, const float2* __restrict__ thf_g,
      const float2* __restrict__ thi_g, const float2* __restrict__ wmix,
      int layer, float2* __restrict__ zi){
  __shared__ __align__(16) char sm[40960];
  float2* th  = (float2*)sm;            // 3072 f2: thf (A) then thi (C)
  float2* xch = (float2*)(sm + 24576);  // 2048 f2 staging (A)
  float2* mixL= (float2*)(sm + 24576);  // [24 j][64 o] (B->C), aliases xch
  int tid = threadIdx.x;
  int b = blockIdx.x / 12, ky = blockIdx.x % 12;
  int wv = tid >> 6, lane = tid & 63;
  for (int f = tid; f < 3072; f += 256) th[f] = thf_g[f];
  // Stage A: h-DFT. acc[q] = xft[j=q*4+wv][c=lane]
  float2 acc[6];
  #pragma unroll
  for (int q = 0; q < 6; q++) acc[q] = make_float2(0.f, 0.f);
  long base = (long)b*98304 + ky*64;
  for (int ch = 0; ch < 4; ch++){
    __syncthreads();
    for (int f = tid; f < 2048; f += 256){
      int hh = f >> 6, c = f & 63;
      long idx = base + (long)(ch*32 + hh)*768 + c;
      float2 v = s0[idx];
      if (dual){ float2 u = s1[idx]; v.x += u.x; v.y += u.y; }
      xch[f] = v;
    }
    __syncthreads();
    for (int hh = 0; hh < 32; hh++){
      float2 v = xch[hh*64 + lane];
      int hg = ch*32 + hh;
      #pragma unroll
      for (int q = 0; q < 6; q++){
        float2 t = th[hg*24 + q*4 + wv];
        acc[q].x += t.x*v.x - t.y*v.y;
        acc[q].y += t.x*v.y + t.y*v.x;
      }
    }
  }
  __syncthreads();                      // A done: xch & thf dead after here
  for (int f = tid; f < 3072; f += 256) th[f] = thi_g[f];   // stage thi
  // Stage B: mode-mix, register-resident via shfl
  float2 mout[6];
  #pragma unroll
  for (int q = 0; q < 6; q++){
    int j = q*4 + wv;
    const float2* wj = wmix + (((long)layer*288 + j*12 + ky))*4096;
    float re = 0.f, im = 0.f;
    #pragma unroll 8
    for (int i = 0; i < 64; i++){
      float vr = __shfl(acc[q].x, i);
      float vi = __shfl(acc[q].y, i);
      float2 ww = wj[i*64 + lane];
      re += vr*ww.x - vi*ww.y;
      im += vr*ww.y + vi*ww.x;
    }
    mout[q] = make_float2(re, im);
  }
  #pragma unroll
  for (int q = 0; q < 6; q++) mixL[(q*4 + wv)*64 + lane] = mout[q];
  __syncthreads();                      // mixL + thi ready
  // Stage C: inverse h-DFT
  float2 cr[24];
  #pragma unroll
  for (int j = 0; j < 24; j++) cr[j] = mixL[j*64 + lane];
  for (int qq = 0; qq < 32; qq++){
    int h = qq*4 + wv;
    float re = 0.f, im = 0.f;
    #pragma unroll
    for (int j = 0; j < 24; j++){
      float2 t = th[h*24 + j];
      re += t.x*cr[j].x - t.y*cr[j].y;
      im += t.x*cr[j].y + t.y*cr[j].x;
    }
    zi[((long)b*128 + h)*768 + ky*64 + lane] = make_float2(re, im);
  }
}

// ------- MFMA: inverse-w + skip + bias + (gelu), in place on x,
//         fused next-layer partial w-DFT via MFMA (twA hi/lo) ----------------
__global__ __launch_bounds__(256) void k_iw_mfma(f16_t* __restrict__ x,
      const float2* __restrict__ zi, const float* __restrict__ ws_w,
      const float* __restrict__ ws_b, const f16_t* __restrict__ twzh,
      const f16_t* __restrict__ twA, float2* __restrict__ fp0,
      float2* __restrict__ fp1, int layer, int act, int dodft){
  __shared__ __align__(16) char sm[52736];
  f16_t* A  = (f16_t*)sm;                   // [128][136] phase1
  f16_t* Bm = (f16_t*)(sm + 34816);         // [64][136]  phase1
  float* sb = (float*)(sm + 52224);         // [64]
  f16_t* Obt  = (f16_t*)sm;                 // [64 c][136 w-pad] phase2 (dodft)
  f16_t* twA_l= (f16_t*)(sm + 17408);       // [2 hl][32 m][136 k-pad]
  int tid = threadIdx.x;
  int blk = blockIdx.x;
  int half = blk & 1;
  long bh = blk >> 1;                       // b*128 + h
  int w0 = half*128;
  const f16_t* xrow = x + (bh*256 + w0)*64;
  for (int f = tid; f < 1024; f += 256){    // x part, 16B copies
    int px = f >> 3, c8 = (f & 7)*8;
    *(float4*)((char*)A + (px*136 + c8)*2) = *(const float4*)(xrow + px*64 + c8);
  }
  for (int f = tid; f < 4096; f += 256){    // twz + zero pad (pow2, no div)
    int px = f >> 5, k = f & 31;
    if (k < 24){
      f16_t v = twzh[(w0+px)*32 + k];
      A[px*136 + 64 + k] = v;
      A[px*136 + 88 + k] = v;
      A[px*136 + 112 + k] = (f16_t)0.f;
    }
  }
  const float* wsl = ws_w + (long)layer*4096;
  for (int f = tid; f < 1024; f += 256){    // B ws part
    int o = f >> 4, c4 = f & 15;
    float4 v = *(const float4*)(wsl + o*64 + c4*4);
    f16_t* d = Bm + o*136 + c4*4;
    d[0]=(f16_t)v.x; d[1]=(f16_t)v.y; d[2]=(f16_t)v.z; d[3]=(f16_t)v.w;
  }
  const float2* zrow = zi + bh*768;
  for (int f = tid; f < 768; f += 256){     // B z hi/lo
    int o = f & 63, ky = f >> 6;
    float2 v = zrow[ky*64 + o];
    f16_t hr = (f16_t)v.x; f16_t hi_ = (f16_t)v.y;
    Bm[o*136 + 64 + ky] = hr;
    Bm[o*136 + 76 + ky] = hi_;
    Bm[o*136 + 88 + ky] = (f16_t)(v.x - (float)hr);
    Bm[o*136 +100 + ky] = (f16_t)(v.y - (float)hi_);
  }
  for (int f = tid; f < 2048; f += 256){    // B zero pad (pow2, no div)
    int o = f >> 5, k = f & 31;
    if (k < 24) Bm[o*136 + 112 + k] = (f16_t)0.f;
  }
  if (tid < 64) sb[tid] = ws_b[layer*64 + tid];
  __syncthreads();
  int lane = tid & 63, wv = tid >> 6;
  int n15 = lane & 15, quad = lane >> 4;
  int n = wv*16 + n15;
  half8 bfr[4];
  #pragma unroll
  for (int kc = 0; kc < 4; kc++)
    bfr[kc] = *(const half8*)(Bm + n*136 + kc*32 + quad*8);
  floatx4 acc[8];
  #pragma unroll
  for (int mt = 0; mt < 8; mt++){
    floatx4 c = {0.f,0.f,0.f,0.f};
    #pragma unroll
    for (int kc = 0; kc < 4; kc++){
      half8 a = *(const half8*)(A + (mt*16 + n15)*136 + kc*32 + quad*8);
      c = __builtin_amdgcn_mfma_f32_16x16x32_f16(a, bfr[kc], c, 0, 0, 0);
    }
    acc[mt] = c;
  }
  float bias = sb[n];
  __syncthreads();                           // A/Bm dead -> Obt, twA_l
  f16_t* xo = x + (bh*256 + w0)*64;
  #pragma unroll
  for (int mt = 0; mt < 8; mt++){
    half4 hv;
    #pragma unroll
    for (int r = 0; r < 4; r++){
      float v = acc[mt][r] + bias;
      if (act) v = gelu_f(v);
      hv[r] = (f16_t)v;
      xo[(mt*16 + quad*4 + r)*64 + n] = hv[r];
    }
    if (dodft) *(half4*)(Obt + n*136 + mt*16 + quad*4) = hv;
  }
  if (dodft){                                // stage twA (this half), re-strided
    const f16_t* tsrc = twA + half*8192;
    for (int f = tid; f < 1024; f += 256){
      int hl = f >> 9, m = (f >> 4) & 31, kc8 = f & 15;
      *(float4*)(twA_l + hl*4352 + m*136 + kc8*8) = *(const float4*)(tsrc + f*8);
    }
    __syncthreads();
    half8 bfr2[4];
    #pragma unroll
    for (int ks = 0; ks < 4; ks++)
      bfr2[ks] = *(const half8*)(Obt + n*136 + ks*32 + quad*8);
    floatx4 dacc[2];
    dacc[0] = (floatx4){0.f,0.f,0.f,0.f};
    dacc[1] = (floatx4){0.f,0.f,0.f,0.f};
    #pragma unroll
    for (int hl = 0; hl < 2; hl++){
      #pragma unroll
      for (int mt = 0; mt < 2; mt++){
        #pragma unroll
        for (int ks = 0; ks < 4; ks++){
          half8 a = *(const half8*)(twA_l + hl*4352 + (mt*16 + n15)*136
                                    + ks*32 + quad*8);
          dacc[mt] = __builtin_amdgcn_mfma_f32_16x16x32_f16(a, bfr2[ks],
                                                            dacc[mt], 0,0,0);
        }
      }
    }
    float2* dst = half ? fp1 : fp0;
    #pragma unroll
    for (int mt = 0; mt < 2; mt++){
      int m0 = mt*16 + quad*4;
      if (m0 < 24){
        int ky0 = m0 >> 1;
        dst[bh*768 + ky0*64 + n]     = make_float2(dacc[mt][0], dacc[mt][1]);
        dst[bh*768 + (ky0+1)*64 + n] = make_float2(dacc[mt][2], dacc[mt][3]);
      }
    }
  }
}

// ------- MFMA conv 3x3 (per-batch weights) + gelu + head, fused; 64-px tiles -
__global__ __launch_bounds__(256) void k_conv_head(const f16_t* __restrict__ x,
      const float* __restrict__ ext, const f16_t* __restrict__ wT,
      const float* __restrict__ tb, const f16_t* __restrict__ f1T,
      const float* __restrict__ f1_b, const f16_t* __restrict__ f2T,
      const float* __restrict__ f2_b, const f16_t* __restrict__ f3T,
      const float* __restrict__ f3_b, float* __restrict__ out){
  __shared__ __align__(16) char sm[37632];
  f16_t* hf   = (f16_t*)sm;                 // [64][72]
  f16_t* z1   = (f16_t*)(sm + 9216);        // [64][136]
  f16_t* z2   = (f16_t*)(sm + 26624);       // [64][72]
  float* tbs  = (float*)(sm + 35840);
  float* f1bs = (float*)(sm + 36096);
  float* f2bs = (float*)(sm + 36608);
  f16_t* f3s  = (f16_t*)(sm + 36864);
  float* f3bs = (float*)(sm + 37120);
  f16_t* xt   = (f16_t*)sm;                 // [3][66][72] (conv phase)

  int tid = threadIdx.x;
  int blk = blockIdx.x;
  int wc = blk & 3, h = (blk >> 2) & 127, b = blk >> 9;
  int w0 = wc*64;
  int t_idx = (int)ext[b*6+3] - 5;

  if (tid < 64) tbs[tid] = tb[t_idx*64 + tid];
  else if (tid < 192) f1bs[tid-64] = f1_b[tid-64];
  else f2bs[tid-192] = f2_b[tid-192];
  if (tid < 128) f3s[tid] = f3T[tid];
  if (tid < 2) f3bs[tid] = f3_b[tid];

  for (int f = tid; f < 1584; f += 256){    // xt: 3 rows x 66 px x 8 chunks, 16B
    int c8 = f & 7, r = f >> 3;
    int dy = r/66, pxl = r%66;
    int hh = h - 1 + dy, wg = w0 - 1 + pxl;
    float4 v = {0.f,0.f,0.f,0.f};
    if (hh >= 0 && hh < HH_ && wg >= 0 && wg < WW_)
      v = *(const float4*)(x + (((long)b*HH_ + hh)*WW_ + wg)*64 + c8*8);
    *(float4*)(xt + (dy*66 + pxl)*72 + c8*8) = v;
  }
  __syncthreads();

  int lane = tid & 63, wv = tid >> 6;
  int n15 = lane & 15, quad = lane >> 4;

  floatx4 acc[4];
  #pragma unroll
  for (int mt = 0; mt < 4; mt++) acc[mt] = (floatx4){0.f,0.f,0.f,0.f};
  const f16_t* wTt = wT + (long)t_idx*36864;
  for (int tap = 0; tap < 9; tap++){
    int dy = tap/3, dx = tap%3;
    const f16_t* wrow = wTt + (tap*64 + wv*16 + n15)*64;
    #pragma unroll
    for (int kc = 0; kc < 2; kc++){
      half8 bfrag = *(const half8*)(wrow + kc*32 + quad*8);
      #pragma unroll
      for (int mt = 0; mt < 4; mt++){
        int p = mt*16 + n15 + dx;
        half8 a = *(const half8*)(xt + (dy*66 + p)*72 + kc*32 + quad*8);
        acc[mt] = __builtin_amdgcn_mfma_f32_16x16x32_f16(a, bfrag, acc[mt], 0,0,0);
      }
    }
  }
  __syncthreads();                           // xt dead
  {
    int n = wv*16 + n15;
    float bias = tbs[n];
    #pragma unroll
    for (int mt = 0; mt < 4; mt++){
      #pragma unroll
      for (int r = 0; r < 4; r++){
        int m = mt*16 + quad*4 + r;
        hf[m*72 + n] = (f16_t)gelu_f(acc[mt][r] + bias);
      }
    }
  }
  __syncthreads();
  // z1 = gelu(hf . f1^T + f1_b): M=64 N=128 K=64
  #pragma unroll
  for (int nt = 0; nt < 2; nt++){
    int n = wv*32 + nt*16 + n15;
    float bias = f1bs[n];
    half8 bf0 = *(const half8*)(f1T + n*64 + quad*8);
    half8 bf1 = *(const half8*)(f1T + n*64 + 32 + quad*8);
    #pragma unroll
    for (int mt = 0; mt < 4; mt++){
      floatx4 c = {0.f,0.f,0.f,0.f};
      half8 a0 = *(const half8*)(hf + (mt*16 + n15)*72 + quad*8);
      half8 a1 = *(const half8*)(hf + (mt*16 + n15)*72 + 32 + quad*8);
      c = __builtin_amdgcn_mfma_f32_16x16x32_f16(a0, bf0, c, 0,0,0);
      c = __builtin_amdgcn_mfma_f32_16x16x32_f16(a1, bf1, c, 0,0,0);
      #pragma unroll
      for (int r = 0; r < 4; r++){
        int m = mt*16 + quad*4 + r;
        z1[m*136 + n] = (f16_t)gelu_f(c[r] + bias);
      }
    }
  }
  __syncthreads();
  // z2 = gelu(z1 . f2^T + f2_b): M=64 N=64 K=128
  {
    int n = wv*16 + n15;
    float bias = f2bs[n];
    half8 bf[4];
    #pragma unroll
    for (int kc = 0; kc < 4; kc++)
      bf[kc] = *(const half8*)(f2T + n*128 + kc*32 + quad*8);
    #pragma unroll
    for (int mt = 0; mt < 4; mt++){
      floatx4 c = {0.f,0.f,0.f,0.f};
      #pragma unroll
      for (int kc = 0; kc < 4; kc++){
        half8 a = *(const half8*)(z1 + (mt*16 + n15)*136 + kc*32 + quad*8);
        c = __builtin_amdgcn_mfma_f32_16x16x32_f16(a, bf[kc], c, 0,0,0);
      }
      #pragma unroll
      for (int r = 0; r < 4; r++){
        int m = mt*16 + quad*4 + r;
        z2[m*72 + n] = (f16_t)gelu_f(c[r] + bias);
      }
    }
  }
  __syncthreads();
  // f3: out[px][0..1]
  if (tid < 128){
    int px = tid >> 1, oo = tid & 1;
    const f16_t* zr = z2 + px*72;
    const f16_t* fr = f3s + oo*64;
    float a = f3bs[oo];
    #pragma unroll
    for (int g = 0; g < 8; g++){
      half8 zv = *(const half8*)(zr + g*8);
      half8 wv2 = *(const half8*)(fr + g*8);
      #pragma unroll
      for (int q = 0; q < 8; q++) a += (float)zv[q]*(float)wv2[q];
    }
    out[(((long)b*HH_ + h)*WW_ + w0 + px)*2 + oo] = a;
  }
}

extern "C" void kernel_launch(void* const* d_in, const int* in_sizes, int n_in,
                              void* d_out, int out_size, void* d_ws, size_t ws_size,
                              hipStream_t stream){
  const float* inp     = (const float*)d_in[0];
  const float* ext     = (const float*)d_in[1];
  const float* enc_w   = (const float*)d_in[2];
  const float* enc_b   = (const float*)d_in[3];
  const float* w1r     = (const float*)d_in[4];
  const float* w1i     = (const float*)d_in[5];
  const float* w2r     = (const float*)d_in[6];
  const float* w2i     = (const float*)d_in[7];
  const float* ws_w    = (const float*)d_in[8];
  const float* ws_b    = (const float*)d_in[9];
  const float* day_emb = (const float*)d_in[10];
  const float* hour_emb= (const float*)d_in[11];
  const float* e1_w    = (const float*)d_in[12];
  const float* e1_b    = (const float*)d_in[13];
  const float* e2_w    = (const float*)d_in[14];
  const float* e2_b    = (const float*)d_in[15];
  const float* tw      = (const float*)d_in[16];
  const float* tb      = (const float*)d_in[17];
  const float* f1_w    = (const float*)d_in[18];
  const float* f1_b    = (const float*)d_in[19];
  const float* f2_w    = (const float*)d_in[20];
  const float* f2_b    = (const float*)d_in[21];
  const float* f3_w    = (const float*)d_in[22];
  const float* f3_b    = (const float*)d_in[23];
  float* outp = (float*)d_out;

  const size_t need = 248652032;
  if (ws_size < need){
    k_diag<<<dim3(1), dim3(64), 0, stream>>>(outp, (float)(ws_size >> 20));
    return;
  }
  char* p = (char*)d_ws;
  f16_t*  x    = (f16_t*)(p);                    // 134217728 B
  float2* fp0  = (float2*)(p + 134217728);       // 25165824 B
  float2* fp1  = (float2*)(p + 159383552);       // 25165824 B
  float2* zi   = (float2*)(p + 184549376);       // 25165824 B
  float2* twf  = (float2*)(p + 209715200);       // 24576 B
  float2* thf  = (float2*)(p + 209739776);       // 24576 B
  float2* thi  = (float2*)(p + 209764352);       // 24576 B
  f16_t*  twzh = (f16_t*)(p + 209788928);        // 16384 B
  f16_t*  wT   = (f16_t*)(p + 209805312);        // 1032192 B
  f16_t*  f1T  = (f16_t*)(p + 210837504);        // 16384 B
  f16_t*  f2T  = (f16_t*)(p + 210853888);        // 16384 B
  f16_t*  f3T  = (f16_t*)(p + 210870272);        // 256 B
  float2* wmix = (float2*)(p + 210870528);       // 37748736 B
  f16_t*  twA  = (f16_t*)(p + 248619264);        // 32768 B

  k_prep<<<dim3(1001), dim3(256), 0, stream>>>(twf, thf, thi, twzh,
      f1_w, f2_w, f3_w, f1T, f2T, f3T, tw, wT, w1r, w1i, w2r, w2i, wmix, twA);
  k_gxdft<<<dim3(4096), dim3(256), 0, stream>>>(ext, day_emb, hour_emb,
      e1_w, e1_b, e2_w, e2_b, inp, enc_w, enc_b, twA, x, fp0, fp1);
  for (int l = 0; l < 4; l++){
    k_spec<<<dim3(384), dim3(256), 0, stream>>>(fp0, fp1, 1,
                                                thf, thi, wmix, l, zi);
    k_iw_mfma<<<dim3(8192), dim3(256), 0, stream>>>(x, zi, ws_w, ws_b, twzh,
                       twA, fp0, fp1, l, (l < 3) ? 1 : 0, (l < 3) ? 1 : 0);
  }
  k_conv_head<<<dim3(16384), dim3(256), 0, stream>>>(x, ext, wT, tb,
                     f1T, f1_b, f2T, f2_b, f3T, f3_b, outp);
}